// Round 6
// baseline (243.503 us; speedup 1.0000x reference)
//
#include <hip/hip_runtime.h>

// MHSA: x[4,2048,1024] fp32, pos[2048] i32, qkv_w[3072,1024] fp32, o_w[1024,1024] fp32
// out[4,2048,1024] fp32.  bf16 MFMA internally (threshold is bf16-floored).
// R13: (a) RoPE tables packed as float2 (cos,sin interleaved) -> qkv Q/K
//      epilogue VMEM gathers 288->160 per thread (-44%); (b) gemm_out
//      retiled 256x128, grid 32x8 = 256 blocks = ONE uniform round
//      (was 128^2 x 512 blocks = 2 rounds), uniform 3 loads/wave/K-tile,
//      counted vmcnt(3), R8 phase protocol, 72 KB LDS, acc[8][2].
//      gemm_qkv loop = R8 (proven); flash v7 + cvt_pk unchanged.

#define DM   1024
#define NH   16
#define HD   64
#define SEQL 2048
#define BATCH 4
#define QKV_ELEMS 8388608           // 4*16*2048*64 per tensor

using short8 = __attribute__((ext_vector_type(8))) short;
using f32x4  = __attribute__((ext_vector_type(4))) float;
typedef unsigned short u16;

// s_waitcnt with only vmcnt active: expcnt=7, lgkmcnt=15 (no-wait)
#define WAIT_VM(n) __builtin_amdgcn_s_waitcnt(0x0F70 | (n))
// s_waitcnt lgkmcnt(0) only: vmcnt=63, expcnt=7
#define WAIT_LGKM0() __builtin_amdgcn_s_waitcnt(0xC07F)
#define BARRIER()  __builtin_amdgcn_s_barrier()

// hardware packed f32->bf16 (RNE), 1 instruction per pair (T12 recipe; no builtin)
__device__ __forceinline__ unsigned cvtpk(float lo, float hi) {
    unsigned r;
    asm("v_cvt_pk_bf16_f32 %0, %1, %2" : "=v"(r) : "v"(lo), "v"(hi));
    return r;
}
__device__ __forceinline__ u16 f2bf1(float x) {
    unsigned r;
    asm("v_cvt_pk_bf16_f32 %0, %1, %1" : "=v"(r) : "v"(x));
    return (u16)r;
}
__device__ __forceinline__ float fexp2(float x) {
#if __has_builtin(__builtin_amdgcn_exp2f)
    return __builtin_amdgcn_exp2f(x);
#else
    return __expf(x * 0.6931471805599453f);
#endif
}

// async global->LDS, 16B per lane; LDS dest = wave-uniform base + lane*16
__device__ __forceinline__ void load16(const void* g, void* l) {
    __builtin_amdgcn_global_load_lds(
        (__attribute__((address_space(1))) unsigned int*)(unsigned long long)g,
        (__attribute__((address_space(3))) unsigned int*)(unsigned int)(unsigned long long)l,
        16, 0, 0);
}

// ---------------- prep: fp32->bf16 (x, qkv_w, o_w) + RoPE float2 table --------
__global__ __launch_bounds__(256) void prep(const float* __restrict__ x, u16* __restrict__ xb,
                                            const float* __restrict__ qw, u16* __restrict__ wb,
                                            const float* __restrict__ ow, u16* __restrict__ owb,
                                            float2* __restrict__ cst) {
    int bx = blockIdx.x;
    if (bx < 12288) {
        const float* in; u16* out; int i;
        if (bx < 8192)       { in = x;  out = xb;  i = bx * 256 + threadIdx.x; }
        else if (bx < 11264) { in = qw; out = wb;  i = (bx - 8192) * 256 + threadIdx.x; }
        else                 { in = ow; out = owb; i = (bx - 11264) * 256 + threadIdx.x; }
        float4 v = ((const float4*)in)[i];
        uint2 o;
        o.x = cvtpk(v.x, v.y);
        o.y = cvtpk(v.z, v.w);
        ((uint2*)out)[i] = o;
    } else {
        int t = (bx - 12288) * 256 + threadIdx.x;   // 65536 = 2048 pos x 32 d2
        int j = t & 31, pos = t >> 5;
        float freq = exp2f((float)j * (-2.0f / 64.0f) * 13.287712379549449f);
        float ang = (float)pos * freq;
        float2 cs; cs.x = cosf(ang); cs.y = sinf(ang);
        cst[t] = cs;
    }
}

// -------- QKV GEMM (256^2 tile, R8): Q,K -> [b][h][s][d] fused RoPE; V -> vt --
// 8 waves (2M x 4N), per-wave 128x64 out, acc[8][4]. BK=32, 3 LDS buffers.
// LDS tile layout: [256 rows][4 chunks of 16B], chunk c holds global chunk
// c ^ ((row>>1)&3)  (staged linearly by global_load_lds from a pre-swizzled
// global address; ds_read applies the same XOR -> 2-way (free) bank access).
__global__ __launch_bounds__(512, 2) void gemm_qkv(const u16* __restrict__ xb,
                                                   const u16* __restrict__ wb,
                                                   u16* __restrict__ qkv,
                                                   u16* __restrict__ vt,
                                                   const int* __restrict__ pos_ids,
                                                   const float2* __restrict__ cst) {
    __shared__ __align__(16) u16 As[3 * 256 * 32];   // 48 KB
    __shared__ __align__(16) u16 Bs[3 * 256 * 32];   // 48 KB
    int tid = threadIdx.x, w = tid >> 6, l = tid & 63;
    int l15 = l & 15, l4 = l >> 4;
    int wr = w >> 2, wc = w & 3;

    // XCD-chunked bijective swizzle: 384 blocks, 8 XCDs -> 48 per chunk.
    int bid = blockIdx.y * 12 + blockIdx.x;
    int swz = (bid & 7) * 48 + (bid >> 3);
    int nI = swz % 12, mI = swz / 12;
    int m0 = mI * 256, n0 = nI * 256;

    // staging: wave w owns rows [32w, 32w+32) of both A and B panels.
    int schunk = ((l & 3) ^ ((l >> 3) & 3)) * 8;
    const u16* gA = xb + (size_t)(m0 + 32 * w + (l >> 2)) * DM + schunk;
    const u16* gB = wb + (size_t)(n0 + 32 * w + (l >> 2)) * DM + schunk;
    char* ldsA = (char*)As + 2048 * w;
    char* ldsB = (char*)Bs + 2048 * w;

    // frag reads: row = base+l15, k-chunk l4 -> LDS chunk l4 ^ ((l15>>1)&3)
    int roff = (l4 ^ ((l15 >> 1) & 3)) * 16;
    int aoff = (128 * wr + l15) * 64 + roff;
    int boff = (64 * wc + l15) * 64 + roff;

    f32x4 acc[8][4];
    f32x4 z = {0.f, 0.f, 0.f, 0.f};
#pragma unroll
    for (int i = 0; i < 8; ++i)
#pragma unroll
        for (int j = 0; j < 4; ++j) acc[i][j] = z;

    // prologue: stage tiles 0,1 -> bufs 0,1 (order: A,A,B,B per tile = FIFO)
#pragma unroll
    for (int t = 0; t < 2; ++t) {
        load16(gA + t * 32,           ldsA + t * 16384);
        load16(gA + t * 32 + 16 * DM, ldsA + t * 16384 + 1024);
        load16(gB + t * 32,           ldsB + t * 16384);
        load16(gB + t * 32 + 16 * DM, ldsB + t * 16384 + 1024);
    }
    WAIT_VM(4);        // tile0 landed; tile1 (4 loads) still in flight
    BARRIER();

    int buf = 0;
    for (int kt = 0; kt < 32; ++kt) {
        const char* bA = (const char*)As + 16384 * buf;
        const char* bB = (const char*)Bs + 16384 * buf;
        int nb = buf + 2; if (nb >= 3) nb -= 3;
        // ---- phase 0: ds-load a[0..3]+b[0..3], stage A of tile kt+2 ----
        short8 a[4], b[4];
#pragma unroll
        for (int i = 0; i < 4; ++i) a[i] = *(const short8*)(bA + aoff + 1024 * i);
#pragma unroll
        for (int j = 0; j < 4; ++j) b[j] = *(const short8*)(bB + boff + 1024 * j);
        if (kt + 2 < 32) {
            load16(gA + (kt + 2) * 32,           ldsA + nb * 16384);
            load16(gA + (kt + 2) * 32 + 16 * DM, ldsA + nb * 16384 + 1024);
        }
        BARRIER();
        WAIT_LGKM0();
        __builtin_amdgcn_s_setprio(1);
#pragma unroll
        for (int i = 0; i < 4; ++i)
#pragma unroll
            for (int j = 0; j < 4; ++j)
                acc[i][j] = __builtin_amdgcn_mfma_f32_16x16x32_bf16(a[i], b[j], acc[i][j], 0, 0, 0);
        __builtin_amdgcn_s_setprio(0);
        BARRIER();
        // ---- phase 1: ds-load a[4..7], stage B of tile kt+2 ----
        short8 a2[4];
#pragma unroll
        for (int i = 0; i < 4; ++i) a2[i] = *(const short8*)(bA + aoff + 1024 * (i + 4));
        if (kt + 2 < 32) {
            load16(gB + (kt + 2) * 32,           ldsB + nb * 16384);
            load16(gB + (kt + 2) * 32 + 16 * DM, ldsB + nb * 16384 + 1024);
        }
        BARRIER();
        WAIT_LGKM0();
        __builtin_amdgcn_s_setprio(1);
#pragma unroll
        for (int i = 0; i < 4; ++i)
#pragma unroll
            for (int j = 0; j < 4; ++j)
                acc[i + 4][j] = __builtin_amdgcn_mfma_f32_16x16x32_bf16(a2[i], b[j], acc[i + 4][j], 0, 0, 0);
        __builtin_amdgcn_s_setprio(0);
        // tile boundary: counted wait — next tile's loads (issued 2 tiles ago)
        // must be done; only tile kt+2's 4 loads may remain in flight.
        if (kt + 2 < 32) WAIT_VM(4); else WAIT_VM(0);
        BARRIER();
        buf = (kt + 1) % 3;
    }

    // ---- epilogue ----  C elem: m = m0+128wr+16i+4*l4+r,  n = n0+64wc+16j+l15
    if (nI >= 8) {
        // V tile: store transposed [b][h][d][s]; r spans 4 consecutive s -> uint2
#pragma unroll
        for (int j = 0; j < 4; ++j) {
            int nv = (n0 - 2048) + 64 * wc + 16 * j + l15;
            int h = nv >> 6, d = nv & 63;
#pragma unroll
            for (int i = 0; i < 8; ++i) {
                int sb = m0 + 128 * wr + 16 * i + 4 * l4;
                int bb = sb >> 11, s = sb & 2047;
                uint2 pk;
                pk.x = cvtpk(acc[i][j][0], acc[i][j][1]);
                pk.y = cvtpk(acc[i][j][2], acc[i][j][3]);
                *(uint2*)&vt[((size_t)(bb * 16 + h) * HD + d) * SEQL + s] = pk;
            }
        }
    } else {
        // Q/K tile: fused RoPE. Pairs (d even, d+1) sit on lanes (l, l^1).
        // Q additionally prescaled by 0.125*log2e (softmax scale + exp2 domain).
        // Tables: float2 (cos,sin) -> one 8B gather per (pos, d2).
        float sc = (nI < 4) ? 0.18033688011112042f : 1.0f;
        u16* base = qkv + (size_t)(nI >> 2) * QKV_ELEMS;
        int h = ((n0 & 1023) >> 6) + wc;
        int d2b = l15 >> 1;
#pragma unroll
        for (int i = 0; i < 8; ++i) {
#pragma unroll
            for (int r = 0; r < 4; ++r) {
                int m = m0 + 128 * wr + 16 * i + 4 * l4 + r;
                int bb = m >> 11, s = m & 2047;
                int pos = pos_ids[s];
                const float2* ct = cst + pos * 32;
                float2 tt[4];
                tt[0] = ct[d2b];      tt[1] = ct[8 + d2b];
                tt[2] = ct[16 + d2b]; tt[3] = ct[24 + d2b];
                u16* orow = base + ((size_t)(bb * 16 + h) * SEQL + s) * HD;
#pragma unroll
                for (int j = 0; j < 4; ++j) {
                    int d = 16 * j + l15;
                    float c  = tt[j].x;
                    float sn = tt[j].y;
                    float v  = acc[i][j][r];
                    float vp = __shfl_xor(v, 1);
                    float o  = (d & 1) ? (vp * sn + v * c) : (v * c - vp * sn);
                    orow[d] = f2bf1(o * sc);
                }
            }
        }
    }
}

// ---------------- out-proj GEMM (256x128 tile, single round): fp32 out --------
// Grid 32x8 = 256 blocks = 1/CU. 8 waves (2M x 4N), per-wave 128x32, acc[8][2].
// Uniform staging: 2 A-loads + 1 B-load per wave per K-tile; counted vmcnt(3).
// Same chunk swizzle + phase protocol as gemm_qkv. LDS 72 KB.
__global__ __launch_bounds__(512, 2) void gemm_out(const u16* __restrict__ ctx,
                                                   const u16* __restrict__ owb,
                                                   float* __restrict__ out) {
    __shared__ __align__(16) u16 As[3 * 256 * 32];   // 48 KB
    __shared__ __align__(16) u16 Bs[3 * 128 * 32];   // 24 KB
    int tid = threadIdx.x, w = tid >> 6, l = tid & 63;
    int l15 = l & 15, l4 = l >> 4;
    int wr = w >> 2, wc = w & 3;

    // XCD-chunked bijective swizzle: 256 blocks, 8 XCDs -> 32 per chunk.
    int bid = blockIdx.y * 8 + blockIdx.x;
    int swz = (bid & 7) * 32 + (bid >> 3);
    int mI = swz >> 3, nI = swz & 7;
    int m0 = mI * 256, n0 = nI * 128;

    int schunk = ((l & 3) ^ ((l >> 3) & 3)) * 8;
    const u16* gA = ctx + (size_t)(m0 + 32 * w + (l >> 2)) * DM + schunk;
    const u16* gB = owb + (size_t)(n0 + 16 * w + (l >> 2)) * DM + schunk;
    char* ldsA = (char*)As + 2048 * w;
    char* ldsB = (char*)Bs + 1024 * w;

    int roff = (l4 ^ ((l15 >> 1) & 3)) * 16;
    int aoff = (128 * wr + l15) * 64 + roff;
    int boff = (32 * wc + l15) * 64 + roff;

    f32x4 acc[8][2];
    f32x4 z = {0.f, 0.f, 0.f, 0.f};
#pragma unroll
    for (int i = 0; i < 8; ++i)
#pragma unroll
        for (int j = 0; j < 2; ++j) acc[i][j] = z;

    // prologue: tiles 0,1 (A,A,B per tile); vmcnt(3) -> tile0 landed
#pragma unroll
    for (int t = 0; t < 2; ++t) {
        load16(gA + t * 32,           ldsA + t * 16384);
        load16(gA + t * 32 + 16 * DM, ldsA + t * 16384 + 1024);
        load16(gB + t * 32,           ldsB + t * 8192);
    }
    WAIT_VM(3);
    BARRIER();

    int buf = 0;
    for (int kt = 0; kt < 32; ++kt) {
        const char* bA = (const char*)As + 16384 * buf;
        const char* bB = (const char*)Bs + 8192 * buf;
        int nb = buf + 2; if (nb >= 3) nb -= 3;
        // ---- phase 0: ds-load a[0..3]+b[0..1], stage A of tile kt+2 ----
        short8 a[4], b[2];
#pragma unroll
        for (int i = 0; i < 4; ++i) a[i] = *(const short8*)(bA + aoff + 1024 * i);
#pragma unroll
        for (int j = 0; j < 2; ++j) b[j] = *(const short8*)(bB + boff + 1024 * j);
        if (kt + 2 < 32) {
            load16(gA + (kt + 2) * 32,           ldsA + nb * 16384);
            load16(gA + (kt + 2) * 32 + 16 * DM, ldsA + nb * 16384 + 1024);
        }
        BARRIER();
        WAIT_LGKM0();
        __builtin_amdgcn_s_setprio(1);
#pragma unroll
        for (int i = 0; i < 4; ++i)
#pragma unroll
            for (int j = 0; j < 2; ++j)
                acc[i][j] = __builtin_amdgcn_mfma_f32_16x16x32_bf16(a[i], b[j], acc[i][j], 0, 0, 0);
        __builtin_amdgcn_s_setprio(0);
        BARRIER();
        // ---- phase 1: ds-load a[4..7], stage B of tile kt+2 ----
        short8 a2[4];
#pragma unroll
        for (int i = 0; i < 4; ++i) a2[i] = *(const short8*)(bA + aoff + 1024 * (i + 4));
        if (kt + 2 < 32) {
            load16(gB + (kt + 2) * 32, ldsB + nb * 8192);
        }
        BARRIER();
        WAIT_LGKM0();
        __builtin_amdgcn_s_setprio(1);
#pragma unroll
        for (int i = 0; i < 4; ++i)
#pragma unroll
            for (int j = 0; j < 2; ++j)
                acc[i + 4][j] = __builtin_amdgcn_mfma_f32_16x16x32_bf16(a2[i], b[j], acc[i + 4][j], 0, 0, 0);
        __builtin_amdgcn_s_setprio(0);
        if (kt + 2 < 32) WAIT_VM(3); else WAIT_VM(0);
        BARRIER();
        buf = (kt + 1) % 3;
    }

    // epilogue: fp32, m = m0+128wr+16i+4*l4+r, n = n0+32wc+16j+l15
#pragma unroll
    for (int i = 0; i < 8; ++i) {
        int mb = m0 + 128 * wr + 16 * i + 4 * l4;
#pragma unroll
        for (int j = 0; j < 2; ++j) {
            int n = n0 + 32 * wc + 16 * j + l15;
#pragma unroll
            for (int r = 0; r < 4; ++r)
                out[(size_t)(mb + r) * DM + n] = acc[i][j][r];
        }
    }
}

// ---------------- flash attention v7: q-tile 256, 8 waves x 2 groups ----------
// Wave w: q-rows q0+128g+16w..+15 for g in {0,1}. K/V frags loaded once per
// iter, shared by both groups. Fixed-max softmax (Q prescaled).
// v7: dual P-buffers; ordering S0/write0 -> S1/write1 -> vf -> PV0 -> PV1
// hides the P LDS write->read latency under g1's S-MFMAs; setprio around
// MFMA clusters; P-pack via v_cvt_pk_bf16_f32.
__device__ __forceinline__ void flash_pass(int qt, const u16* __restrict__ Qb,
                                           const u16* __restrict__ Kb,
                                           const u16* __restrict__ Vb,
                                           u16* __restrict__ ctx, int bh,
                                           u16* KsB, u16* VsB, u16* PsB) {
    int tid = threadIdx.x, w = tid >> 6, l = tid & 63;
    int l15 = l & 15, l4 = l >> 4;
    int q0 = qt * 256;
    int swz = l15 & 7;
    int b0 = (l4 ^ swz) * 16;

    short8 aq[2][2];
#pragma unroll
    for (int g = 0; g < 2; ++g) {
        const u16* qr = Qb + (size_t)(q0 + 128 * g + 16 * w + l15) * HD;
        aq[g][0] = *(const short8*)&qr[l4 * 8];
        aq[g][1] = *(const short8*)&qr[32 + l4 * 8];
    }
    int srow = l >> 3;
    int sblk = ((l & 7) ^ srow) * 8;
    const u16* gK = Kb + (size_t)(8 * w + srow) * HD + sblk;
    const u16* gV = Vb + (size_t)(8 * w + srow) * SEQL + sblk;
    char* ldsK = (char*)KsB + 1024 * w;
    char* ldsV = (char*)VsB + 1024 * w;
    char* prow0 = (char*)PsB + 2048 * w + l15 * 128;
    char* prow1 = prow0 + 16384;

    f32x4 z = {0.f, 0.f, 0.f, 0.f};
    f32x4 O[2][4] = {{z, z, z, z}, {z, z, z, z}};
    float lsum[2] = {0.f, 0.f};
    int nk = 4 * qt + 4;
    int d0 = 4 * qt + (w >> 2);        // g0 diagonal iter (g1: +2)
    int rowlim = 16 * (w & 3) + l15;

    BARRIER();   // prior pass's LDS reads consumed
#pragma unroll
    for (int t = 0; t < 2; ++t) {
        load16(gK + (size_t)(t * 64) * HD, ldsK + t * 8192);
        load16(gV + t * 64,                ldsV + t * 8192);
    }
    int buf = 0;
    for (int it = 0; it < nk; ++it) {
        if (it < nk - 1) WAIT_VM(2); else WAIT_VM(0);
        BARRIER();
        if (it + 2 < nk) {
            int k0n = (it + 2) * 64;
            int nb = 8192 * ((buf + 2) % 3);
            load16(gK + (size_t)k0n * HD, ldsK + nb);
            load16(gV + k0n,              ldsV + nb);
        }
        if (it <= d0 + 2) {            // else: both groups fully masked
            const char* bK = (const char*)KsB + 8192 * buf;
            const char* bV = (const char*)VsB + 8192 * buf;
            bool g0act = (it <= d0);
            short8 kf[4][2];
#pragma unroll
            for (int c = 0; c < 4; ++c) {
                const char* kr = bK + (16 * c + l15) * 128;
                kf[c][0] = *(const short8*)(kr + b0);
                kf[c][1] = *(const short8*)(kr + (b0 ^ 64));
            }
            // ---- group 0: S, softmax, P-write ----
            if (g0act) {
                f32x4 S[4];
                __builtin_amdgcn_s_setprio(1);
#pragma unroll
                for (int c = 0; c < 4; ++c) {
                    S[c] = __builtin_amdgcn_mfma_f32_16x16x32_bf16(kf[c][0], aq[0][0], z, 0, 0, 0);
                    S[c] = __builtin_amdgcn_mfma_f32_16x16x32_bf16(kf[c][1], aq[0][1], S[c], 0, 0, 0);
                }
                __builtin_amdgcn_s_setprio(0);
                if (it == d0) {
#pragma unroll
                    for (int c = 0; c < 4; ++c)
#pragma unroll
                        for (int r = 0; r < 4; ++r)
                            if (16 * c + 4 * l4 + r > rowlim) S[c][r] = -3e38f;
                }
                float ls = 0.f;
#pragma unroll
                for (int c = 0; c < 4; ++c) {
                    float cs = 0.f;
#pragma unroll
                    for (int r = 0; r < 4; ++r) {
                        float p = fexp2(S[c][r]);
                        S[c][r] = p;
                        cs += p;
                    }
                    ls += cs;
                    uint2 pk;
                    pk.x = cvtpk(S[c][0], S[c][1]);
                    pk.y = cvtpk(S[c][2], S[c][3]);
                    *(uint2*)(prow0 + ((((2 * c + (l4 >> 1)) ^ swz) << 4) | ((l4 & 1) << 3))) = pk;
                }
                lsum[0] += ls;
            }
            // ---- group 1: S, softmax, P-write (always active under guard) ----
            {
                f32x4 S[4];
                __builtin_amdgcn_s_setprio(1);
#pragma unroll
                for (int c = 0; c < 4; ++c) {
                    S[c] = __builtin_amdgcn_mfma_f32_16x16x32_bf16(kf[c][0], aq[1][0], z, 0, 0, 0);
                    S[c] = __builtin_amdgcn_mfma_f32_16x16x32_bf16(kf[c][1], aq[1][1], S[c], 0, 0, 0);
                }
                __builtin_amdgcn_s_setprio(0);
                if (it == d0 + 2) {
#pragma unroll
                    for (int c = 0; c < 4; ++c)
#pragma unroll
                        for (int r = 0; r < 4; ++r)
                            if (16 * c + 4 * l4 + r > rowlim) S[c][r] = -3e38f;
                }
                float ls = 0.f;
#pragma unroll
                for (int c = 0; c < 4; ++c) {
                    float cs = 0.f;
#pragma unroll
                    for (int r = 0; r < 4; ++r) {
                        float p = fexp2(S[c][r]);
                        S[c][r] = p;
                        cs += p;
                    }
                    ls += cs;
                    uint2 pk;
                    pk.x = cvtpk(S[c][0], S[c][1]);
                    pk.y = cvtpk(S[c][2], S[c][3]);
                    *(uint2*)(prow1 + ((((2 * c + (l4 >> 1)) ^ swz) << 4) | ((l4 & 1) << 3))) = pk;
                }
                lsum[1] += ls;
            }
            // ---- V frags (between writes and reads: more latency cover) ----
            short8 vf[4][2];
#pragma unroll
            for (int c = 0; c < 4; ++c) {
                const char* vr = bV + (16 * c + l15) * 128;
                vf[c][0] = *(const short8*)(vr + b0);
                vf[c][1] = *(const short8*)(vr + (b0 ^ 64));
            }
            // ---- PV group 0 ----
            if (g0act) {
                short8 ap0 = *(const short8*)(prow0 + b0);
                short8 ap1 = *(const short8*)(prow0 + (b0 ^ 64));
                __builtin_amdgcn_s_setprio(1);
#pragma unroll
                for (int nt = 0; nt < 4; ++nt) {
                    O[0][nt] = __builtin_amdgcn_mfma_f32_16x16x32_bf16(ap0, vf[nt][0], O[0][nt], 0, 0, 0);
                    O[0][nt] = __builtin_amdgcn_mfma_f32_16x16x32_bf16(ap1, vf[nt][1], O[0][nt], 0, 0, 0);
                }
                __builtin_amdgcn_s_setprio(0);
            }
            // ---- PV group 1 ----
            {
                short8 bp0 = *(const short8*)(prow1 + b0);
                short8 bp1 = *(const short8*)(prow1 + (b0 ^ 64));
                __builtin_amdgcn_s_setprio(1);
#pragma unroll
                for (int nt = 0; nt < 4; ++nt) {
                    O[1][nt] = __builtin_amdgcn_mfma_f32_16x16x32_bf16(bp0, vf[nt][0], O[1][nt], 0, 0, 0);
                    O[1][nt] = __builtin_amdgcn_mfma_f32_16x16x32_bf16(bp1, vf[nt][1], O[1][nt], 0, 0, 0);
                }
                __builtin_amdgcn_s_setprio(0);
            }
        }
        buf = (buf + 1) % 3;
    }
    // epilogue: ctx[b][s][h*64+d] bf16
    int b = bh >> 4, h = bh & 15;
#pragma unroll
    for (int g = 0; g < 2; ++g) {
        float ls = lsum[g];
        ls += __shfl_xor(ls, 16);
        ls += __shfl_xor(ls, 32);
        float linv[4];
#pragma unroll
        for (int r = 0; r < 4; ++r) linv[r] = 1.0f / __shfl(ls, 20 * l4 + r);
#pragma unroll
        for (int nt = 0; nt < 4; ++nt) {
            int d = 16 * nt + l15;
#pragma unroll
            for (int r = 0; r < 4; ++r) {
                int s = q0 + 128 * g + 16 * w + 4 * l4 + r;
                ctx[((size_t)(b * SEQL + s)) * DM + h * 64 + d] = f2bf1(O[g][nt][r] * linv[r]);
            }
        }
    }
}

// Block x in [0,4): q-tiles 7-x then x -> uniform 36 iters per block.
__global__ __launch_bounds__(512, 2) void flash_attn(const u16* __restrict__ Q,
                                                     const u16* __restrict__ K,
                                                     const u16* __restrict__ Vt,
                                                     u16* __restrict__ ctx) {
    __shared__ __align__(16) u16 Ks[3][64 * 64];      // 24 KB
    __shared__ __align__(16) u16 Vs[3][64 * 64];      // 24 KB
    __shared__ __align__(16) u16 Ps[2][8][16 * 64];   // 32 KB (dual P buffers)
    int bh = blockIdx.y, pair = blockIdx.x;
    const u16* Qb = Q + (size_t)bh * SEQL * HD;
    const u16* Kb = K + (size_t)bh * SEQL * HD;
    const u16* Vb = Vt + (size_t)bh * HD * SEQL;
    flash_pass(7 - pair, Qb, Kb, Vb, ctx, bh, &Ks[0][0], &Vs[0][0], &Ps[0][0][0]);
    flash_pass(pair,     Qb, Kb, Vb, ctx, bh, &Ks[0][0], &Vs[0][0], &Ps[0][0][0]);
}

extern "C" void kernel_launch(void* const* d_in, const int* in_sizes, int n_in,
                              void* d_out, int out_size, void* d_ws, size_t ws_size,
                              hipStream_t stream) {
    const float* x     = (const float*)d_in[0];
    const int*   pos   = (const int*)d_in[1];
    const float* qkv_w = (const float*)d_in[2];
    const float* o_w   = (const float*)d_in[3];
    float* out = (float*)d_out;

    char* ws = (char*)d_ws;
    u16*    xb  = (u16*)(ws);              // 16 MB (reused as ctx)
    u16*    wb  = (u16*)(ws + 16777216);   // 6 MB
    u16*    owb = (u16*)(ws + 23068672);   // 2 MB
    float2* cst = (float2*)(ws + 25165824);// 512 KB (cos,sin interleaved)
    u16*    qkv = (u16*)(ws + 25690112);   // 32 MB (Q,K)
    u16*    vt  = (u16*)(ws + 76021760);   // 16 MB
    u16*    ctx = xb;                      // alias: xb dead after gemm_qkv

    prep<<<12544, 256, 0, stream>>>(x, xb, qkv_w, wb, o_w, owb, cst);
    gemm_qkv<<<dim3(12, 32), 512, 0, stream>>>(xb, wb, qkv, vt, pos, cst);
    flash_attn<<<dim3(4, 64), 512, 0, stream>>>(qkv, qkv + QKV_ELEMS, vt, ctx);
    gemm_out<<<dim3(8, 32), 512, 0, stream>>>(ctx, owb, out);
}

// Round 10
// 241.652 us; speedup vs baseline: 1.0077x; 1.0077x over previous
//
#include <hip/hip_runtime.h>

// MHSA: x[4,2048,1024] fp32, pos[2048] i32, qkv_w[3072,1024] fp32, o_w[1024,1024] fp32
// out[4,2048,1024] fp32.  bf16 MFMA internally (threshold is bf16-floored).
// R17: banking round — best proven-passing composite after the v8/v9 flash
//      regeometry failed twice (R14 NaN, R15/16 absmax 0.092; bug not found
//      by inspection, branch abandoned). prep+gemm_qkv = R13 (float2 RoPE
//      table), flash = v7 (512-thd, q-tile 256, dual-P, cvt_pk; proven in
//      R12/R13), gemm_out = R12 gemm128_core. Expected ~R12's 237 us.

#define DM   1024
#define NH   16
#define HD   64
#define SEQL 2048
#define BATCH 4
#define QKV_ELEMS 8388608           // 4*16*2048*64 per tensor

using short8 = __attribute__((ext_vector_type(8))) short;
using f32x4  = __attribute__((ext_vector_type(4))) float;
typedef unsigned short u16;

// s_waitcnt with only vmcnt active: expcnt=7, lgkmcnt=15 (no-wait)
#define WAIT_VM(n) __builtin_amdgcn_s_waitcnt(0x0F70 | (n))
// s_waitcnt lgkmcnt(0) only: vmcnt=63, expcnt=7
#define WAIT_LGKM0() __builtin_amdgcn_s_waitcnt(0xC07F)
#define BARRIER()  __builtin_amdgcn_s_barrier()

// hardware packed f32->bf16 (RNE), 1 instruction per pair (T12 recipe; no builtin)
__device__ __forceinline__ unsigned cvtpk(float lo, float hi) {
    unsigned r;
    asm("v_cvt_pk_bf16_f32 %0, %1, %2" : "=v"(r) : "v"(lo), "v"(hi));
    return r;
}
__device__ __forceinline__ u16 f2bf1(float x) {
    unsigned r;
    asm("v_cvt_pk_bf16_f32 %0, %1, %1" : "=v"(r) : "v"(x));
    return (u16)r;
}
__device__ __forceinline__ float fexp2(float x) {
#if __has_builtin(__builtin_amdgcn_exp2f)
    return __builtin_amdgcn_exp2f(x);
#else
    return __expf(x * 0.6931471805599453f);
#endif
}

// async global->LDS, 16B per lane; LDS dest = wave-uniform base + lane*16
__device__ __forceinline__ void load16(const void* g, void* l) {
    __builtin_amdgcn_global_load_lds(
        (__attribute__((address_space(1))) unsigned int*)(unsigned long long)g,
        (__attribute__((address_space(3))) unsigned int*)(unsigned int)(unsigned long long)l,
        16, 0, 0);
}

// ---------------- prep: fp32->bf16 (x, qkv_w, o_w) + RoPE float2 table --------
__global__ __launch_bounds__(256) void prep(const float* __restrict__ x, u16* __restrict__ xb,
                                            const float* __restrict__ qw, u16* __restrict__ wb,
                                            const float* __restrict__ ow, u16* __restrict__ owb,
                                            float2* __restrict__ cst) {
    int bx = blockIdx.x;
    if (bx < 12288) {
        const float* in; u16* out; int i;
        if (bx < 8192)       { in = x;  out = xb;  i = bx * 256 + threadIdx.x; }
        else if (bx < 11264) { in = qw; out = wb;  i = (bx - 8192) * 256 + threadIdx.x; }
        else                 { in = ow; out = owb; i = (bx - 11264) * 256 + threadIdx.x; }
        float4 v = ((const float4*)in)[i];
        uint2 o;
        o.x = cvtpk(v.x, v.y);
        o.y = cvtpk(v.z, v.w);
        ((uint2*)out)[i] = o;
    } else {
        int t = (bx - 12288) * 256 + threadIdx.x;   // 65536 = 2048 pos x 32 d2
        int j = t & 31, pos = t >> 5;
        float freq = exp2f((float)j * (-2.0f / 64.0f) * 13.287712379549449f);
        float ang = (float)pos * freq;
        float2 cs; cs.x = cosf(ang); cs.y = sinf(ang);
        cst[t] = cs;
    }
}

// ---------------- 128x128-tile bf16 GEMM core, BK=32, triple-buffered ----------
__device__ __forceinline__ void gemm128_core(const u16* __restrict__ A,
                                             const u16* __restrict__ B,
                                             int K, int m0, int n0,
                                             u16* As, u16* Bs, f32x4 acc[4][4]) {
    int tid = threadIdx.x, w = tid >> 6, l = tid & 63;
    int l15 = l & 15, l4 = l >> 4;
    int wm = w >> 1, wn = w & 1;
    int r0 = 32 * w + (l >> 2);
    int gblk = ((l & 3) ^ ((l >> 4) & 3)) * 8;
    const u16* gA0 = A + (size_t)(m0 + r0) * K + gblk;
    const u16* gA1 = gA0 + (size_t)16 * K;
    const u16* gB0 = B + (size_t)(n0 + r0) * K + gblk;
    const u16* gB1 = gB0 + (size_t)16 * K;
    char* ldsA = (char*)As + 2048 * w;
    char* ldsB = (char*)Bs + 2048 * w;
    int fo = ((l4 ^ (l15 >> 2)) & 3) * 16;
    f32x4 z = {0.f, 0.f, 0.f, 0.f};
#pragma unroll
    for (int i = 0; i < 4; ++i)
#pragma unroll
        for (int j = 0; j < 4; ++j) acc[i][j] = z;
    int nk = K >> 5;
#pragma unroll
    for (int t = 0; t < 2; ++t) {
        int ko = t << 5, nb = t * 8192;
        load16(gA0 + ko, ldsA + nb); load16(gA1 + ko, ldsA + nb + 1024);
        load16(gB0 + ko, ldsB + nb); load16(gB1 + ko, ldsB + nb + 1024);
    }
    int buf = 0;
    for (int kt = 0; kt < nk; ++kt) {
        if (kt < nk - 1) WAIT_VM(4); else WAIT_VM(0);
        BARRIER();
        if (kt + 2 < nk) {
            int ko = (kt + 2) << 5;
            int nb = 8192 * ((buf + 2) % 3);
            load16(gA0 + ko, ldsA + nb); load16(gA1 + ko, ldsA + nb + 1024);
            load16(gB0 + ko, ldsB + nb); load16(gB1 + ko, ldsB + nb + 1024);
        }
        const char* bA = (const char*)As + 8192 * buf;
        const char* bB = (const char*)Bs + 8192 * buf;
        short8 a[4], b[4];
#pragma unroll
        for (int i = 0; i < 4; ++i)
            a[i] = *(const short8*)(bA + (64 * wm + 16 * i + l15) * 64 + fo);
#pragma unroll
        for (int j = 0; j < 4; ++j)
            b[j] = *(const short8*)(bB + (64 * wn + 16 * j + l15) * 64 + fo);
#pragma unroll
        for (int i = 0; i < 4; ++i)
#pragma unroll
            for (int j = 0; j < 4; ++j)
                acc[i][j] = __builtin_amdgcn_mfma_f32_16x16x32_bf16(a[i], b[j], acc[i][j], 0, 0, 0);
        buf = (buf + 1) % 3;
    }
}

// -------- QKV GEMM (256^2 tile, R8): Q,K -> [b][h][s][d] fused RoPE; V -> vt --
__global__ __launch_bounds__(512, 2) void gemm_qkv(const u16* __restrict__ xb,
                                                   const u16* __restrict__ wb,
                                                   u16* __restrict__ qkv,
                                                   u16* __restrict__ vt,
                                                   const int* __restrict__ pos_ids,
                                                   const float2* __restrict__ cst) {
    __shared__ __align__(16) u16 As[3 * 256 * 32];   // 48 KB
    __shared__ __align__(16) u16 Bs[3 * 256 * 32];   // 48 KB
    int tid = threadIdx.x, w = tid >> 6, l = tid & 63;
    int l15 = l & 15, l4 = l >> 4;
    int wr = w >> 2, wc = w & 3;

    // XCD-chunked bijective swizzle: 384 blocks, 8 XCDs -> 48 per chunk.
    int bid = blockIdx.y * 12 + blockIdx.x;
    int swz = (bid & 7) * 48 + (bid >> 3);
    int nI = swz % 12, mI = swz / 12;
    int m0 = mI * 256, n0 = nI * 256;

    int schunk = ((l & 3) ^ ((l >> 3) & 3)) * 8;
    const u16* gA = xb + (size_t)(m0 + 32 * w + (l >> 2)) * DM + schunk;
    const u16* gB = wb + (size_t)(n0 + 32 * w + (l >> 2)) * DM + schunk;
    char* ldsA = (char*)As + 2048 * w;
    char* ldsB = (char*)Bs + 2048 * w;

    int roff = (l4 ^ ((l15 >> 1) & 3)) * 16;
    int aoff = (128 * wr + l15) * 64 + roff;
    int boff = (64 * wc + l15) * 64 + roff;

    f32x4 acc[8][4];
    f32x4 z = {0.f, 0.f, 0.f, 0.f};
#pragma unroll
    for (int i = 0; i < 8; ++i)
#pragma unroll
        for (int j = 0; j < 4; ++j) acc[i][j] = z;

#pragma unroll
    for (int t = 0; t < 2; ++t) {
        load16(gA + t * 32,           ldsA + t * 16384);
        load16(gA + t * 32 + 16 * DM, ldsA + t * 16384 + 1024);
        load16(gB + t * 32,           ldsB + t * 16384);
        load16(gB + t * 32 + 16 * DM, ldsB + t * 16384 + 1024);
    }
    WAIT_VM(4);
    BARRIER();

    int buf = 0;
    for (int kt = 0; kt < 32; ++kt) {
        const char* bA = (const char*)As + 16384 * buf;
        const char* bB = (const char*)Bs + 16384 * buf;
        int nb = buf + 2; if (nb >= 3) nb -= 3;
        // ---- phase 0: ds-load a[0..3]+b[0..3], stage A of tile kt+2 ----
        short8 a[4], b[4];
#pragma unroll
        for (int i = 0; i < 4; ++i) a[i] = *(const short8*)(bA + aoff + 1024 * i);
#pragma unroll
        for (int j = 0; j < 4; ++j) b[j] = *(const short8*)(bB + boff + 1024 * j);
        if (kt + 2 < 32) {
            load16(gA + (kt + 2) * 32,           ldsA + nb * 16384);
            load16(gA + (kt + 2) * 32 + 16 * DM, ldsA + nb * 16384 + 1024);
        }
        BARRIER();
        WAIT_LGKM0();
        __builtin_amdgcn_s_setprio(1);
#pragma unroll
        for (int i = 0; i < 4; ++i)
#pragma unroll
            for (int j = 0; j < 4; ++j)
                acc[i][j] = __builtin_amdgcn_mfma_f32_16x16x32_bf16(a[i], b[j], acc[i][j], 0, 0, 0);
        __builtin_amdgcn_s_setprio(0);
        BARRIER();
        // ---- phase 1: ds-load a[4..7], stage B of tile kt+2 ----
        short8 a2[4];
#pragma unroll
        for (int i = 0; i < 4; ++i) a2[i] = *(const short8*)(bA + aoff + 1024 * (i + 4));
        if (kt + 2 < 32) {
            load16(gB + (kt + 2) * 32,           ldsB + nb * 16384);
            load16(gB + (kt + 2) * 32 + 16 * DM, ldsB + nb * 16384 + 1024);
        }
        BARRIER();
        WAIT_LGKM0();
        __builtin_amdgcn_s_setprio(1);
#pragma unroll
        for (int i = 0; i < 4; ++i)
#pragma unroll
            for (int j = 0; j < 4; ++j)
                acc[i + 4][j] = __builtin_amdgcn_mfma_f32_16x16x32_bf16(a2[i], b[j], acc[i + 4][j], 0, 0, 0);
        __builtin_amdgcn_s_setprio(0);
        if (kt + 2 < 32) WAIT_VM(4); else WAIT_VM(0);
        BARRIER();
        buf = (kt + 1) % 3;
    }

    // ---- epilogue ----  C elem: m = m0+128wr+16i+4*l4+r,  n = n0+64wc+16j+l15
    if (nI >= 8) {
#pragma unroll
        for (int j = 0; j < 4; ++j) {
            int nv = (n0 - 2048) + 64 * wc + 16 * j + l15;
            int h = nv >> 6, d = nv & 63;
#pragma unroll
            for (int i = 0; i < 8; ++i) {
                int sb = m0 + 128 * wr + 16 * i + 4 * l4;
                int bb = sb >> 11, s = sb & 2047;
                uint2 pk;
                pk.x = cvtpk(acc[i][j][0], acc[i][j][1]);
                pk.y = cvtpk(acc[i][j][2], acc[i][j][3]);
                *(uint2*)&vt[((size_t)(bb * 16 + h) * HD + d) * SEQL + s] = pk;
            }
        }
    } else {
        float sc = (nI < 4) ? 0.18033688011112042f : 1.0f;
        u16* base = qkv + (size_t)(nI >> 2) * QKV_ELEMS;
        int h = ((n0 & 1023) >> 6) + wc;
        int d2b = l15 >> 1;
#pragma unroll
        for (int i = 0; i < 8; ++i) {
#pragma unroll
            for (int r = 0; r < 4; ++r) {
                int m = m0 + 128 * wr + 16 * i + 4 * l4 + r;
                int bb = m >> 11, s = m & 2047;
                int pos = pos_ids[s];
                const float2* ct = cst + pos * 32;
                float2 tt[4];
                tt[0] = ct[d2b];      tt[1] = ct[8 + d2b];
                tt[2] = ct[16 + d2b]; tt[3] = ct[24 + d2b];
                u16* orow = base + ((size_t)(bb * 16 + h) * SEQL + s) * HD;
#pragma unroll
                for (int j = 0; j < 4; ++j) {
                    int d = 16 * j + l15;
                    float c  = tt[j].x;
                    float sn = tt[j].y;
                    float v  = acc[i][j][r];
                    float vp = __shfl_xor(v, 1);
                    float o  = (d & 1) ? (vp * sn + v * c) : (v * c - vp * sn);
                    orow[d] = f2bf1(o * sc);
                }
            }
        }
    }
}

// ---------------- out-proj GEMM (R12): fp32 out [m][n] ----------------
__global__ __launch_bounds__(256) void gemm_out(const u16* __restrict__ ctx,
                                                const u16* __restrict__ owb,
                                                float* __restrict__ out) {
    __shared__ __align__(16) u16 As[3 * 128 * 32], Bs[3 * 128 * 32];
    f32x4 acc[4][4];
    int m0 = blockIdx.y * 128, n0 = blockIdx.x * 128;
    gemm128_core(ctx, owb, DM, m0, n0, As, Bs, acc);
    int l = threadIdx.x & 63, w = threadIdx.x >> 6;
    int l15 = l & 15, l4 = l >> 4;
    int wm = w >> 1, wn = w & 1;
#pragma unroll
    for (int i = 0; i < 4; ++i) {
        int mb = m0 + 64 * wm + 16 * i + 4 * l4;
#pragma unroll
        for (int j = 0; j < 4; ++j) {
            int n = n0 + 64 * wn + 16 * j + l15;
#pragma unroll
            for (int r = 0; r < 4; ++r)
                out[(size_t)(mb + r) * DM + n] = acc[i][j][r];
        }
    }
}

// ---------------- flash attention v7: q-tile 256, 8 waves x 2 groups ----------
// Wave w: q-rows q0+128g+16w..+15 for g in {0,1}. K/V frags loaded once per
// iter, shared by both groups. Fixed-max softmax (Q prescaled).
// Dual P-buffers; ordering S0/write0 -> S1/write1 -> vf -> PV0 -> PV1;
// setprio around MFMA clusters; P-pack via v_cvt_pk_bf16_f32.
__device__ __forceinline__ void flash_pass(int qt, const u16* __restrict__ Qb,
                                           const u16* __restrict__ Kb,
                                           const u16* __restrict__ Vb,
                                           u16* __restrict__ ctx, int bh,
                                           u16* KsB, u16* VsB, u16* PsB) {
    int tid = threadIdx.x, w = tid >> 6, l = tid & 63;
    int l15 = l & 15, l4 = l >> 4;
    int q0 = qt * 256;
    int swz = l15 & 7;
    int b0 = (l4 ^ swz) * 16;

    short8 aq[2][2];
#pragma unroll
    for (int g = 0; g < 2; ++g) {
        const u16* qr = Qb + (size_t)(q0 + 128 * g + 16 * w + l15) * HD;
        aq[g][0] = *(const short8*)&qr[l4 * 8];
        aq[g][1] = *(const short8*)&qr[32 + l4 * 8];
    }
    int srow = l >> 3;
    int sblk = ((l & 7) ^ srow) * 8;
    const u16* gK = Kb + (size_t)(8 * w + srow) * HD + sblk;
    const u16* gV = Vb + (size_t)(8 * w + srow) * SEQL + sblk;
    char* ldsK = (char*)KsB + 1024 * w;
    char* ldsV = (char*)VsB + 1024 * w;
    char* prow0 = (char*)PsB + 2048 * w + l15 * 128;
    char* prow1 = prow0 + 16384;

    f32x4 z = {0.f, 0.f, 0.f, 0.f};
    f32x4 O[2][4] = {{z, z, z, z}, {z, z, z, z}};
    float lsum[2] = {0.f, 0.f};
    int nk = 4 * qt + 4;
    int d0 = 4 * qt + (w >> 2);        // g0 diagonal iter (g1: +2)
    int rowlim = 16 * (w & 3) + l15;

    BARRIER();   // prior pass's LDS reads consumed
#pragma unroll
    for (int t = 0; t < 2; ++t) {
        load16(gK + (size_t)(t * 64) * HD, ldsK + t * 8192);
        load16(gV + t * 64,                ldsV + t * 8192);
    }
    int buf = 0;
    for (int it = 0; it < nk; ++it) {
        if (it < nk - 1) WAIT_VM(2); else WAIT_VM(0);
        BARRIER();
        if (it + 2 < nk) {
            int k0n = (it + 2) * 64;
            int nb = 8192 * ((buf + 2) % 3);
            load16(gK + (size_t)k0n * HD, ldsK + nb);
            load16(gV + k0n,              ldsV + nb);
        }
        if (it <= d0 + 2) {            // else: both groups fully masked
            const char* bK = (const char*)KsB + 8192 * buf;
            const char* bV = (const char*)VsB + 8192 * buf;
            bool g0act = (it <= d0);
            short8 kf[4][2];
#pragma unroll
            for (int c = 0; c < 4; ++c) {
                const char* kr = bK + (16 * c + l15) * 128;
                kf[c][0] = *(const short8*)(kr + b0);
                kf[c][1] = *(const short8*)(kr + (b0 ^ 64));
            }
            // ---- group 0: S, softmax, P-write ----
            if (g0act) {
                f32x4 S[4];
                __builtin_amdgcn_s_setprio(1);
#pragma unroll
                for (int c = 0; c < 4; ++c) {
                    S[c] = __builtin_amdgcn_mfma_f32_16x16x32_bf16(kf[c][0], aq[0][0], z, 0, 0, 0);
                    S[c] = __builtin_amdgcn_mfma_f32_16x16x32_bf16(kf[c][1], aq[0][1], S[c], 0, 0, 0);
                }
                __builtin_amdgcn_s_setprio(0);
                if (it == d0) {
#pragma unroll
                    for (int c = 0; c < 4; ++c)
#pragma unroll
                        for (int r = 0; r < 4; ++r)
                            if (16 * c + 4 * l4 + r > rowlim) S[c][r] = -3e38f;
                }
                float ls = 0.f;
#pragma unroll
                for (int c = 0; c < 4; ++c) {
                    float cs = 0.f;
#pragma unroll
                    for (int r = 0; r < 4; ++r) {
                        float p = fexp2(S[c][r]);
                        S[c][r] = p;
                        cs += p;
                    }
                    ls += cs;
                    uint2 pk;
                    pk.x = cvtpk(S[c][0], S[c][1]);
                    pk.y = cvtpk(S[c][2], S[c][3]);
                    *(uint2*)(prow0 + ((((2 * c + (l4 >> 1)) ^ swz) << 4) | ((l4 & 1) << 3))) = pk;
                }
                lsum[0] += ls;
            }
            // ---- group 1: S, softmax, P-write (always active under guard) ----
            {
                f32x4 S[4];
                __builtin_amdgcn_s_setprio(1);
#pragma unroll
                for (int c = 0; c < 4; ++c) {
                    S[c] = __builtin_amdgcn_mfma_f32_16x16x32_bf16(kf[c][0], aq[1][0], z, 0, 0, 0);
                    S[c] = __builtin_amdgcn_mfma_f32_16x16x32_bf16(kf[c][1], aq[1][1], S[c], 0, 0, 0);
                }
                __builtin_amdgcn_s_setprio(0);
                if (it == d0 + 2) {
#pragma unroll
                    for (int c = 0; c < 4; ++c)
#pragma unroll
                        for (int r = 0; r < 4; ++r)
                            if (16 * c + 4 * l4 + r > rowlim) S[c][r] = -3e38f;
                }
                float ls = 0.f;
#pragma unroll
                for (int c = 0; c < 4; ++c) {
                    float cs = 0.f;
#pragma unroll
                    for (int r = 0; r < 4; ++r) {
                        float p = fexp2(S[c][r]);
                        S[c][r] = p;
                        cs += p;
                    }
                    ls += cs;
                    uint2 pk;
                    pk.x = cvtpk(S[c][0], S[c][1]);
                    pk.y = cvtpk(S[c][2], S[c][3]);
                    *(uint2*)(prow1 + ((((2 * c + (l4 >> 1)) ^ swz) << 4) | ((l4 & 1) << 3))) = pk;
                }
                lsum[1] += ls;
            }
            // ---- V frags (between writes and reads: more latency cover) ----
            short8 vf[4][2];
#pragma unroll
            for (int c = 0; c < 4; ++c) {
                const char* vr = bV + (16 * c + l15) * 128;
                vf[c][0] = *(const short8*)(vr + b0);
                vf[c][1] = *(const short8*)(vr + (b0 ^ 64));
            }
            // ---- PV group 0 ----
            if (g0act) {
                short8 ap0 = *(const short8*)(prow0 + b0);
                short8 ap1 = *(const short8*)(prow0 + (b0 ^ 64));
                __builtin_amdgcn_s_setprio(1);
#pragma unroll
                for (int nt = 0; nt < 4; ++nt) {
                    O[0][nt] = __builtin_amdgcn_mfma_f32_16x16x32_bf16(ap0, vf[nt][0], O[0][nt], 0, 0, 0);
                    O[0][nt] = __builtin_amdgcn_mfma_f32_16x16x32_bf16(ap1, vf[nt][1], O[0][nt], 0, 0, 0);
                }
                __builtin_amdgcn_s_setprio(0);
            }
            // ---- PV group 1 ----
            {
                short8 bp0 = *(const short8*)(prow1 + b0);
                short8 bp1 = *(const short8*)(prow1 + (b0 ^ 64));
                __builtin_amdgcn_s_setprio(1);
#pragma unroll
                for (int nt = 0; nt < 4; ++nt) {
                    O[1][nt] = __builtin_amdgcn_mfma_f32_16x16x32_bf16(bp0, vf[nt][0], O[1][nt], 0, 0, 0);
                    O[1][nt] = __builtin_amdgcn_mfma_f32_16x16x32_bf16(bp1, vf[nt][1], O[1][nt], 0, 0, 0);
                }
                __builtin_amdgcn_s_setprio(0);
            }
        }
        buf = (buf + 1) % 3;
    }
    // epilogue: ctx[b][s][h*64+d] bf16
    int b = bh >> 4, h = bh & 15;
#pragma unroll
    for (int g = 0; g < 2; ++g) {
        float ls = lsum[g];
        ls += __shfl_xor(ls, 16);
        ls += __shfl_xor(ls, 32);
        float linv[4];
#pragma unroll
        for (int r = 0; r < 4; ++r) linv[r] = 1.0f / __shfl(ls, 20 * l4 + r);
#pragma unroll
        for (int nt = 0; nt < 4; ++nt) {
            int d = 16 * nt + l15;
#pragma unroll
            for (int r = 0; r < 4; ++r) {
                int s = q0 + 128 * g + 16 * w + 4 * l4 + r;
                ctx[((size_t)(b * SEQL + s)) * DM + h * 64 + d] = f2bf1(O[g][nt][r] * linv[r]);
            }
        }
    }
}

// Block x in [0,4): q-tiles 7-x then x -> uniform 36 iters per block.
__global__ __launch_bounds__(512, 2) void flash_attn(const u16* __restrict__ Q,
                                                     const u16* __restrict__ K,
                                                     const u16* __restrict__ Vt,
                                                     u16* __restrict__ ctx) {
    __shared__ __align__(16) u16 Ks[3][64 * 64];      // 24 KB
    __shared__ __align__(16) u16 Vs[3][64 * 64];      // 24 KB
    __shared__ __align__(16) u16 Ps[2][8][16 * 64];   // 32 KB (dual P buffers)
    int bh = blockIdx.y, pair = blockIdx.x;
    const u16* Qb = Q + (size_t)bh * SEQL * HD;
    const u16* Kb = K + (size_t)bh * SEQL * HD;
    const u16* Vb = Vt + (size_t)bh * HD * SEQL;
    flash_pass(7 - pair, Qb, Kb, Vb, ctx, bh, &Ks[0][0], &Vs[0][0], &Ps[0][0][0]);
    flash_pass(pair,     Qb, Kb, Vb, ctx, bh, &Ks[0][0], &Vs[0][0], &Ps[0][0][0]);
}

extern "C" void kernel_launch(void* const* d_in, const int* in_sizes, int n_in,
                              void* d_out, int out_size, void* d_ws, size_t ws_size,
                              hipStream_t stream) {
    const float* x     = (const float*)d_in[0];
    const int*   pos   = (const int*)d_in[1];
    const float* qkv_w = (const float*)d_in[2];
    const float* o_w   = (const float*)d_in[3];
    float* out = (float*)d_out;

    char* ws = (char*)d_ws;
    u16*    xb  = (u16*)(ws);              // 16 MB (reused as ctx)
    u16*    wb  = (u16*)(ws + 16777216);   // 6 MB
    u16*    owb = (u16*)(ws + 23068672);   // 2 MB
    float2* cst = (float2*)(ws + 25165824);// 512 KB (cos,sin interleaved)
    u16*    qkv = (u16*)(ws + 25690112);   // 32 MB (Q,K)
    u16*    vt  = (u16*)(ws + 76021760);   // 16 MB
    u16*    ctx = xb;                      // alias: xb dead after gemm_qkv

    prep<<<12544, 256, 0, stream>>>(x, xb, qkv_w, wb, o_w, owb, cst);
    gemm_qkv<<<dim3(12, 32), 512, 0, stream>>>(xb, wb, qkv, vt, pos, cst);
    flash_attn<<<dim3(4, 64), 512, 0, stream>>>(qkv, qkv + QKV_ELEMS, vt, ctx);
    gemm_out<<<dim3(8, 64), 256, 0, stream>>>(ctx, owb, out);
}

// Round 11
// 238.859 us; speedup vs baseline: 1.0194x; 1.0117x over previous
//
#include <hip/hip_runtime.h>

// MHSA: x[4,2048,1024] fp32, pos[2048] i32, qkv_w[3072,1024] fp32, o_w[1024,1024] fp32
// out[4,2048,1024] fp32.  bf16 MFMA internally (threshold is bf16-floored).
// R18: gemm_qkv K-loop ported to gemm128_core's PROVEN 1-barrier protocol
//      (ds-read all 12 frags -> stage kt+2 -> lgkm -> 32-MFMA cluster ->
//      vmcnt(4) -> barrier), replacing R8's 2-phase 4-barrier loop: the loop
//      is >90% sync-stall (3840 cyc/K-tile vs ~320 MFMA), so halving barrier
//      count should cut qkv 77 -> ~65 us. Same 3-buffer invariants, same
//      staging/swizzle/epilogue. flash v7 / gemm_out / prep = R17 (banked).

#define DM   1024
#define NH   16
#define HD   64
#define SEQL 2048
#define BATCH 4
#define QKV_ELEMS 8388608           // 4*16*2048*64 per tensor

using short8 = __attribute__((ext_vector_type(8))) short;
using f32x4  = __attribute__((ext_vector_type(4))) float;
typedef unsigned short u16;

// s_waitcnt with only vmcnt active: expcnt=7, lgkmcnt=15 (no-wait)
#define WAIT_VM(n) __builtin_amdgcn_s_waitcnt(0x0F70 | (n))
// s_waitcnt lgkmcnt(0) only: vmcnt=63, expcnt=7
#define WAIT_LGKM0() __builtin_amdgcn_s_waitcnt(0xC07F)
#define BARRIER()  __builtin_amdgcn_s_barrier()

// hardware packed f32->bf16 (RNE), 1 instruction per pair (T12 recipe; no builtin)
__device__ __forceinline__ unsigned cvtpk(float lo, float hi) {
    unsigned r;
    asm("v_cvt_pk_bf16_f32 %0, %1, %2" : "=v"(r) : "v"(lo), "v"(hi));
    return r;
}
__device__ __forceinline__ u16 f2bf1(float x) {
    unsigned r;
    asm("v_cvt_pk_bf16_f32 %0, %1, %1" : "=v"(r) : "v"(x));
    return (u16)r;
}
__device__ __forceinline__ float fexp2(float x) {
#if __has_builtin(__builtin_amdgcn_exp2f)
    return __builtin_amdgcn_exp2f(x);
#else
    return __expf(x * 0.6931471805599453f);
#endif
}

// async global->LDS, 16B per lane; LDS dest = wave-uniform base + lane*16
__device__ __forceinline__ void load16(const void* g, void* l) {
    __builtin_amdgcn_global_load_lds(
        (__attribute__((address_space(1))) unsigned int*)(unsigned long long)g,
        (__attribute__((address_space(3))) unsigned int*)(unsigned int)(unsigned long long)l,
        16, 0, 0);
}

// ---------------- prep: fp32->bf16 (x, qkv_w, o_w) + RoPE float2 table --------
__global__ __launch_bounds__(256) void prep(const float* __restrict__ x, u16* __restrict__ xb,
                                            const float* __restrict__ qw, u16* __restrict__ wb,
                                            const float* __restrict__ ow, u16* __restrict__ owb,
                                            float2* __restrict__ cst) {
    int bx = blockIdx.x;
    if (bx < 12288) {
        const float* in; u16* out; int i;
        if (bx < 8192)       { in = x;  out = xb;  i = bx * 256 + threadIdx.x; }
        else if (bx < 11264) { in = qw; out = wb;  i = (bx - 8192) * 256 + threadIdx.x; }
        else                 { in = ow; out = owb; i = (bx - 11264) * 256 + threadIdx.x; }
        float4 v = ((const float4*)in)[i];
        uint2 o;
        o.x = cvtpk(v.x, v.y);
        o.y = cvtpk(v.z, v.w);
        ((uint2*)out)[i] = o;
    } else {
        int t = (bx - 12288) * 256 + threadIdx.x;   // 65536 = 2048 pos x 32 d2
        int j = t & 31, pos = t >> 5;
        float freq = exp2f((float)j * (-2.0f / 64.0f) * 13.287712379549449f);
        float ang = (float)pos * freq;
        float2 cs; cs.x = cosf(ang); cs.y = sinf(ang);
        cst[t] = cs;
    }
}

// ---------------- 128x128-tile bf16 GEMM core, BK=32, triple-buffered ----------
__device__ __forceinline__ void gemm128_core(const u16* __restrict__ A,
                                             const u16* __restrict__ B,
                                             int K, int m0, int n0,
                                             u16* As, u16* Bs, f32x4 acc[4][4]) {
    int tid = threadIdx.x, w = tid >> 6, l = tid & 63;
    int l15 = l & 15, l4 = l >> 4;
    int wm = w >> 1, wn = w & 1;
    int r0 = 32 * w + (l >> 2);
    int gblk = ((l & 3) ^ ((l >> 4) & 3)) * 8;
    const u16* gA0 = A + (size_t)(m0 + r0) * K + gblk;
    const u16* gA1 = gA0 + (size_t)16 * K;
    const u16* gB0 = B + (size_t)(n0 + r0) * K + gblk;
    const u16* gB1 = gB0 + (size_t)16 * K;
    char* ldsA = (char*)As + 2048 * w;
    char* ldsB = (char*)Bs + 2048 * w;
    int fo = ((l4 ^ (l15 >> 2)) & 3) * 16;
    f32x4 z = {0.f, 0.f, 0.f, 0.f};
#pragma unroll
    for (int i = 0; i < 4; ++i)
#pragma unroll
        for (int j = 0; j < 4; ++j) acc[i][j] = z;
    int nk = K >> 5;
#pragma unroll
    for (int t = 0; t < 2; ++t) {
        int ko = t << 5, nb = t * 8192;
        load16(gA0 + ko, ldsA + nb); load16(gA1 + ko, ldsA + nb + 1024);
        load16(gB0 + ko, ldsB + nb); load16(gB1 + ko, ldsB + nb + 1024);
    }
    int buf = 0;
    for (int kt = 0; kt < nk; ++kt) {
        if (kt < nk - 1) WAIT_VM(4); else WAIT_VM(0);
        BARRIER();
        if (kt + 2 < nk) {
            int ko = (kt + 2) << 5;
            int nb = 8192 * ((buf + 2) % 3);
            load16(gA0 + ko, ldsA + nb); load16(gA1 + ko, ldsA + nb + 1024);
            load16(gB0 + ko, ldsB + nb); load16(gB1 + ko, ldsB + nb + 1024);
        }
        const char* bA = (const char*)As + 8192 * buf;
        const char* bB = (const char*)Bs + 8192 * buf;
        short8 a[4], b[4];
#pragma unroll
        for (int i = 0; i < 4; ++i)
            a[i] = *(const short8*)(bA + (64 * wm + 16 * i + l15) * 64 + fo);
#pragma unroll
        for (int j = 0; j < 4; ++j)
            b[j] = *(const short8*)(bB + (64 * wn + 16 * j + l15) * 64 + fo);
#pragma unroll
        for (int i = 0; i < 4; ++i)
#pragma unroll
            for (int j = 0; j < 4; ++j)
                acc[i][j] = __builtin_amdgcn_mfma_f32_16x16x32_bf16(a[i], b[j], acc[i][j], 0, 0, 0);
        buf = (buf + 1) % 3;
    }
}

// -------- QKV GEMM (256^2 tile): Q,K -> [b][h][s][d] fused RoPE; V -> vt ------
// R18: 1-barrier-per-K-tile loop (gemm128_core's protocol at 256^2 geometry).
// 8 waves (2M x 4N), per-wave 128x64 out, acc[8][4]. BK=32, 3 LDS buffers.
__global__ __launch_bounds__(512, 2) void gemm_qkv(const u16* __restrict__ xb,
                                                   const u16* __restrict__ wb,
                                                   u16* __restrict__ qkv,
                                                   u16* __restrict__ vt,
                                                   const int* __restrict__ pos_ids,
                                                   const float2* __restrict__ cst) {
    __shared__ __align__(16) u16 As[3 * 256 * 32];   // 48 KB
    __shared__ __align__(16) u16 Bs[3 * 256 * 32];   // 48 KB
    int tid = threadIdx.x, w = tid >> 6, l = tid & 63;
    int l15 = l & 15, l4 = l >> 4;
    int wr = w >> 2, wc = w & 3;

    // XCD-chunked bijective swizzle: 384 blocks, 8 XCDs -> 48 per chunk.
    int bid = blockIdx.y * 12 + blockIdx.x;
    int swz = (bid & 7) * 48 + (bid >> 3);
    int nI = swz % 12, mI = swz / 12;
    int m0 = mI * 256, n0 = nI * 256;

    int schunk = ((l & 3) ^ ((l >> 3) & 3)) * 8;
    const u16* gA = xb + (size_t)(m0 + 32 * w + (l >> 2)) * DM + schunk;
    const u16* gB = wb + (size_t)(n0 + 32 * w + (l >> 2)) * DM + schunk;
    char* ldsA = (char*)As + 2048 * w;
    char* ldsB = (char*)Bs + 2048 * w;

    int roff = (l4 ^ ((l15 >> 1) & 3)) * 16;
    int aoff = (128 * wr + l15) * 64 + roff;
    int boff = (64 * wc + l15) * 64 + roff;

    f32x4 acc[8][4];
    f32x4 z = {0.f, 0.f, 0.f, 0.f};
#pragma unroll
    for (int i = 0; i < 8; ++i)
#pragma unroll
        for (int j = 0; j < 4; ++j) acc[i][j] = z;

    // prologue: stage tiles 0,1 -> bufs 0,1
#pragma unroll
    for (int t = 0; t < 2; ++t) {
        load16(gA + t * 32,           ldsA + t * 16384);
        load16(gA + t * 32 + 16 * DM, ldsA + t * 16384 + 1024);
        load16(gB + t * 32,           ldsB + t * 16384);
        load16(gB + t * 32 + 16 * DM, ldsB + t * 16384 + 1024);
    }
    WAIT_VM(4);        // tile0 landed; tile1 (4 loads) still in flight
    BARRIER();

    int buf = 0;
    for (int kt = 0; kt < 32; ++kt) {
        const char* bA = (const char*)As + 16384 * buf;
        const char* bB = (const char*)Bs + 16384 * buf;
        int nb = buf + 2; if (nb >= 3) nb -= 3;
        // ds-read all 12 fragments of this tile
        short8 a[8], b[4];
#pragma unroll
        for (int i = 0; i < 8; ++i) a[i] = *(const short8*)(bA + aoff + 1024 * i);
#pragma unroll
        for (int j = 0; j < 4; ++j) b[j] = *(const short8*)(bB + boff + 1024 * j);
        // stage tile kt+2 (A + B, 4 loads) -- targets buffer nb != buf
        if (kt + 2 < 32) {
            load16(gA + (kt + 2) * 32,           ldsA + nb * 16384);
            load16(gA + (kt + 2) * 32 + 16 * DM, ldsA + nb * 16384 + 1024);
            load16(gB + (kt + 2) * 32,           ldsB + nb * 16384);
            load16(gB + (kt + 2) * 32 + 16 * DM, ldsB + nb * 16384 + 1024);
        }
        WAIT_LGKM0();            // frags in regs (reads of buf complete)
        __builtin_amdgcn_s_setprio(1);
#pragma unroll
        for (int i = 0; i < 8; ++i)
#pragma unroll
            for (int j = 0; j < 4; ++j)
                acc[i][j] = __builtin_amdgcn_mfma_f32_16x16x32_bf16(a[i], b[j], acc[i][j], 0, 0, 0);
        __builtin_amdgcn_s_setprio(0);
        // drain tile kt+1's loads (issued last tile); kt+2's 4 may stay in flight
        if (kt + 2 < 32) WAIT_VM(4); else WAIT_VM(0);
        BARRIER();               // separates reads of buf from next tile's overwrite
        buf = (kt + 1) % 3;
    }

    // ---- epilogue ----  C elem: m = m0+128wr+16i+4*l4+r,  n = n0+64wc+16j+l15
    if (nI >= 8) {
#pragma unroll
        for (int j = 0; j < 4; ++j) {
            int nv = (n0 - 2048) + 64 * wc + 16 * j + l15;
            int h = nv >> 6, d = nv & 63;
#pragma unroll
            for (int i = 0; i < 8; ++i) {
                int sb = m0 + 128 * wr + 16 * i + 4 * l4;
                int bb = sb >> 11, s = sb & 2047;
                uint2 pk;
                pk.x = cvtpk(acc[i][j][0], acc[i][j][1]);
                pk.y = cvtpk(acc[i][j][2], acc[i][j][3]);
                *(uint2*)&vt[((size_t)(bb * 16 + h) * HD + d) * SEQL + s] = pk;
            }
        }
    } else {
        float sc = (nI < 4) ? 0.18033688011112042f : 1.0f;
        u16* base = qkv + (size_t)(nI >> 2) * QKV_ELEMS;
        int h = ((n0 & 1023) >> 6) + wc;
        int d2b = l15 >> 1;
#pragma unroll
        for (int i = 0; i < 8; ++i) {
#pragma unroll
            for (int r = 0; r < 4; ++r) {
                int m = m0 + 128 * wr + 16 * i + 4 * l4 + r;
                int bb = m >> 11, s = m & 2047;
                int pos = pos_ids[s];
                const float2* ct = cst + pos * 32;
                float2 tt[4];
                tt[0] = ct[d2b];      tt[1] = ct[8 + d2b];
                tt[2] = ct[16 + d2b]; tt[3] = ct[24 + d2b];
                u16* orow = base + ((size_t)(bb * 16 + h) * SEQL + s) * HD;
#pragma unroll
                for (int j = 0; j < 4; ++j) {
                    int d = 16 * j + l15;
                    float c  = tt[j].x;
                    float sn = tt[j].y;
                    float v  = acc[i][j][r];
                    float vp = __shfl_xor(v, 1);
                    float o  = (d & 1) ? (vp * sn + v * c) : (v * c - vp * sn);
                    orow[d] = f2bf1(o * sc);
                }
            }
        }
    }
}

// ---------------- out-proj GEMM (R12): fp32 out [m][n] ----------------
__global__ __launch_bounds__(256) void gemm_out(const u16* __restrict__ ctx,
                                                const u16* __restrict__ owb,
                                                float* __restrict__ out) {
    __shared__ __align__(16) u16 As[3 * 128 * 32], Bs[3 * 128 * 32];
    f32x4 acc[4][4];
    int m0 = blockIdx.y * 128, n0 = blockIdx.x * 128;
    gemm128_core(ctx, owb, DM, m0, n0, As, Bs, acc);
    int l = threadIdx.x & 63, w = threadIdx.x >> 6;
    int l15 = l & 15, l4 = l >> 4;
    int wm = w >> 1, wn = w & 1;
#pragma unroll
    for (int i = 0; i < 4; ++i) {
        int mb = m0 + 64 * wm + 16 * i + 4 * l4;
#pragma unroll
        for (int j = 0; j < 4; ++j) {
            int n = n0 + 64 * wn + 16 * j + l15;
#pragma unroll
            for (int r = 0; r < 4; ++r)
                out[(size_t)(mb + r) * DM + n] = acc[i][j][r];
        }
    }
}

// ---------------- flash attention v7: q-tile 256, 8 waves x 2 groups ----------
// Wave w: q-rows q0+128g+16w..+15 for g in {0,1}. K/V frags loaded once per
// iter, shared by both groups. Fixed-max softmax (Q prescaled).
// Dual P-buffers; ordering S0/write0 -> S1/write1 -> vf -> PV0 -> PV1;
// setprio around MFMA clusters; P-pack via v_cvt_pk_bf16_f32.
__device__ __forceinline__ void flash_pass(int qt, const u16* __restrict__ Qb,
                                           const u16* __restrict__ Kb,
                                           const u16* __restrict__ Vb,
                                           u16* __restrict__ ctx, int bh,
                                           u16* KsB, u16* VsB, u16* PsB) {
    int tid = threadIdx.x, w = tid >> 6, l = tid & 63;
    int l15 = l & 15, l4 = l >> 4;
    int q0 = qt * 256;
    int swz = l15 & 7;
    int b0 = (l4 ^ swz) * 16;

    short8 aq[2][2];
#pragma unroll
    for (int g = 0; g < 2; ++g) {
        const u16* qr = Qb + (size_t)(q0 + 128 * g + 16 * w + l15) * HD;
        aq[g][0] = *(const short8*)&qr[l4 * 8];
        aq[g][1] = *(const short8*)&qr[32 + l4 * 8];
    }
    int srow = l >> 3;
    int sblk = ((l & 7) ^ srow) * 8;
    const u16* gK = Kb + (size_t)(8 * w + srow) * HD + sblk;
    const u16* gV = Vb + (size_t)(8 * w + srow) * SEQL + sblk;
    char* ldsK = (char*)KsB + 1024 * w;
    char* ldsV = (char*)VsB + 1024 * w;
    char* prow0 = (char*)PsB + 2048 * w + l15 * 128;
    char* prow1 = prow0 + 16384;

    f32x4 z = {0.f, 0.f, 0.f, 0.f};
    f32x4 O[2][4] = {{z, z, z, z}, {z, z, z, z}};
    float lsum[2] = {0.f, 0.f};
    int nk = 4 * qt + 4;
    int d0 = 4 * qt + (w >> 2);        // g0 diagonal iter (g1: +2)
    int rowlim = 16 * (w & 3) + l15;

    BARRIER();   // prior pass's LDS reads consumed
#pragma unroll
    for (int t = 0; t < 2; ++t) {
        load16(gK + (size_t)(t * 64) * HD, ldsK + t * 8192);
        load16(gV + t * 64,                ldsV + t * 8192);
    }
    int buf = 0;
    for (int it = 0; it < nk; ++it) {
        if (it < nk - 1) WAIT_VM(2); else WAIT_VM(0);
        BARRIER();
        if (it + 2 < nk) {
            int k0n = (it + 2) * 64;
            int nb = 8192 * ((buf + 2) % 3);
            load16(gK + (size_t)k0n * HD, ldsK + nb);
            load16(gV + k0n,              ldsV + nb);
        }
        if (it <= d0 + 2) {            // else: both groups fully masked
            const char* bK = (const char*)KsB + 8192 * buf;
            const char* bV = (const char*)VsB + 8192 * buf;
            bool g0act = (it <= d0);
            short8 kf[4][2];
#pragma unroll
            for (int c = 0; c < 4; ++c) {
                const char* kr = bK + (16 * c + l15) * 128;
                kf[c][0] = *(const short8*)(kr + b0);
                kf[c][1] = *(const short8*)(kr + (b0 ^ 64));
            }
            // ---- group 0: S, softmax, P-write ----
            if (g0act) {
                f32x4 S[4];
                __builtin_amdgcn_s_setprio(1);
#pragma unroll
                for (int c = 0; c < 4; ++c) {
                    S[c] = __builtin_amdgcn_mfma_f32_16x16x32_bf16(kf[c][0], aq[0][0], z, 0, 0, 0);
                    S[c] = __builtin_amdgcn_mfma_f32_16x16x32_bf16(kf[c][1], aq[0][1], S[c], 0, 0, 0);
                }
                __builtin_amdgcn_s_setprio(0);
                if (it == d0) {
#pragma unroll
                    for (int c = 0; c < 4; ++c)
#pragma unroll
                        for (int r = 0; r < 4; ++r)
                            if (16 * c + 4 * l4 + r > rowlim) S[c][r] = -3e38f;
                }
                float ls = 0.f;
#pragma unroll
                for (int c = 0; c < 4; ++c) {
                    float cs = 0.f;
#pragma unroll
                    for (int r = 0; r < 4; ++r) {
                        float p = fexp2(S[c][r]);
                        S[c][r] = p;
                        cs += p;
                    }
                    ls += cs;
                    uint2 pk;
                    pk.x = cvtpk(S[c][0], S[c][1]);
                    pk.y = cvtpk(S[c][2], S[c][3]);
                    *(uint2*)(prow0 + ((((2 * c + (l4 >> 1)) ^ swz) << 4) | ((l4 & 1) << 3))) = pk;
                }
                lsum[0] += ls;
            }
            // ---- group 1: S, softmax, P-write (always active under guard) ----
            {
                f32x4 S[4];
                __builtin_amdgcn_s_setprio(1);
#pragma unroll
                for (int c = 0; c < 4; ++c) {
                    S[c] = __builtin_amdgcn_mfma_f32_16x16x32_bf16(kf[c][0], aq[1][0], z, 0, 0, 0);
                    S[c] = __builtin_amdgcn_mfma_f32_16x16x32_bf16(kf[c][1], aq[1][1], S[c], 0, 0, 0);
                }
                __builtin_amdgcn_s_setprio(0);
                if (it == d0 + 2) {
#pragma unroll
                    for (int c = 0; c < 4; ++c)
#pragma unroll
                        for (int r = 0; r < 4; ++r)
                            if (16 * c + 4 * l4 + r > rowlim) S[c][r] = -3e38f;
                }
                float ls = 0.f;
#pragma unroll
                for (int c = 0; c < 4; ++c) {
                    float cs = 0.f;
#pragma unroll
                    for (int r = 0; r < 4; ++r) {
                        float p = fexp2(S[c][r]);
                        S[c][r] = p;
                        cs += p;
                    }
                    ls += cs;
                    uint2 pk;
                    pk.x = cvtpk(S[c][0], S[c][1]);
                    pk.y = cvtpk(S[c][2], S[c][3]);
                    *(uint2*)(prow1 + ((((2 * c + (l4 >> 1)) ^ swz) << 4) | ((l4 & 1) << 3))) = pk;
                }
                lsum[1] += ls;
            }
            // ---- V frags (between writes and reads: more latency cover) ----
            short8 vf[4][2];
#pragma unroll
            for (int c = 0; c < 4; ++c) {
                const char* vr = bV + (16 * c + l15) * 128;
                vf[c][0] = *(const short8*)(vr + b0);
                vf[c][1] = *(const short8*)(vr + (b0 ^ 64));
            }
            // ---- PV group 0 ----
            if (g0act) {
                short8 ap0 = *(const short8*)(prow0 + b0);
                short8 ap1 = *(const short8*)(prow0 + (b0 ^ 64));
                __builtin_amdgcn_s_setprio(1);
#pragma unroll
                for (int nt = 0; nt < 4; ++nt) {
                    O[0][nt] = __builtin_amdgcn_mfma_f32_16x16x32_bf16(ap0, vf[nt][0], O[0][nt], 0, 0, 0);
                    O[0][nt] = __builtin_amdgcn_mfma_f32_16x16x32_bf16(ap1, vf[nt][1], O[0][nt], 0, 0, 0);
                }
                __builtin_amdgcn_s_setprio(0);
            }
            // ---- PV group 1 ----
            {
                short8 bp0 = *(const short8*)(prow1 + b0);
                short8 bp1 = *(const short8*)(prow1 + (b0 ^ 64));
                __builtin_amdgcn_s_setprio(1);
#pragma unroll
                for (int nt = 0; nt < 4; ++nt) {
                    O[1][nt] = __builtin_amdgcn_mfma_f32_16x16x32_bf16(bp0, vf[nt][0], O[1][nt], 0, 0, 0);
                    O[1][nt] = __builtin_amdgcn_mfma_f32_16x16x32_bf16(bp1, vf[nt][1], O[1][nt], 0, 0, 0);
                }
                __builtin_amdgcn_s_setprio(0);
            }
        }
        buf = (buf + 1) % 3;
    }
    // epilogue: ctx[b][s][h*64+d] bf16
    int b = bh >> 4, h = bh & 15;
#pragma unroll
    for (int g = 0; g < 2; ++g) {
        float ls = lsum[g];
        ls += __shfl_xor(ls, 16);
        ls += __shfl_xor(ls, 32);
        float linv[4];
#pragma unroll
        for (int r = 0; r < 4; ++r) linv[r] = 1.0f / __shfl(ls, 20 * l4 + r);
#pragma unroll
        for (int nt = 0; nt < 4; ++nt) {
            int d = 16 * nt + l15;
#pragma unroll
            for (int r = 0; r < 4; ++r) {
                int s = q0 + 128 * g + 16 * w + 4 * l4 + r;
                ctx[((size_t)(b * SEQL + s)) * DM + h * 64 + d] = f2bf1(O[g][nt][r] * linv[r]);
            }
        }
    }
}

// Block x in [0,4): q-tiles 7-x then x -> uniform 36 iters per block.
__global__ __launch_bounds__(512, 2) void flash_attn(const u16* __restrict__ Q,
                                                     const u16* __restrict__ K,
                                                     const u16* __restrict__ Vt,
                                                     u16* __restrict__ ctx) {
    __shared__ __align__(16) u16 Ks[3][64 * 64];      // 24 KB
    __shared__ __align__(16) u16 Vs[3][64 * 64];      // 24 KB
    __shared__ __align__(16) u16 Ps[2][8][16 * 64];   // 32 KB (dual P buffers)
    int bh = blockIdx.y, pair = blockIdx.x;
    const u16* Qb = Q + (size_t)bh * SEQL * HD;
    const u16* Kb = K + (size_t)bh * SEQL * HD;
    const u16* Vb = Vt + (size_t)bh * HD * SEQL;
    flash_pass(7 - pair, Qb, Kb, Vb, ctx, bh, &Ks[0][0], &Vs[0][0], &Ps[0][0][0]);
    flash_pass(pair,     Qb, Kb, Vb, ctx, bh, &Ks[0][0], &Vs[0][0], &Ps[0][0][0]);
}

extern "C" void kernel_launch(void* const* d_in, const int* in_sizes, int n_in,
                              void* d_out, int out_size, void* d_ws, size_t ws_size,
                              hipStream_t stream) {
    const float* x     = (const float*)d_in[0];
    const int*   pos   = (const int*)d_in[1];
    const float* qkv_w = (const float*)d_in[2];
    const float* o_w   = (const float*)d_in[3];
    float* out = (float*)d_out;

    char* ws = (char*)d_ws;
    u16*    xb  = (u16*)(ws);              // 16 MB (reused as ctx)
    u16*    wb  = (u16*)(ws + 16777216);   // 6 MB
    u16*    owb = (u16*)(ws + 23068672);   // 2 MB
    float2* cst = (float2*)(ws + 25165824);// 512 KB (cos,sin interleaved)
    u16*    qkv = (u16*)(ws + 25690112);   // 32 MB (Q,K)
    u16*    vt  = (u16*)(ws + 76021760);   // 16 MB
    u16*    ctx = xb;                      // alias: xb dead after gemm_qkv

    prep<<<12544, 256, 0, stream>>>(x, xb, qkv_w, wb, o_w, owb, cst);
    gemm_qkv<<<dim3(12, 32), 512, 0, stream>>>(xb, wb, qkv, vt, pos, cst);
    flash_attn<<<dim3(4, 64), 512, 0, stream>>>(qkv, qkv + QKV_ELEMS, vt, ctx);
    gemm_out<<<dim3(8, 64), 256, 0, stream>>>(ctx, owb, out);
}

// Round 12
// 228.883 us; speedup vs baseline: 1.0639x; 1.0436x over previous
//
#include <hip/hip_runtime.h>

// MHSA: x[4,2048,1024] fp32, pos[2048] i32, qkv_w[3072,1024] fp32, o_w[1024,1024] fp32
// out[4,2048,1024] fp32.  bf16 MFMA internally (threshold is bf16-floored).
// R19: three zero-risk remaps on R18 (banked 238.9): (1) flash v7 blocks
//      XCD-clustered via bijective blockIdx remap -- XCD c owns bh
//      {c,c+8,..,c+56}, 8 x 512KB K/V = 4MB = one L2; kernel body untouched.
//      (2) gemm_out XCD-chunked swizzle (T1, 512%8==0). (3) prep grid-stride
//      2048+256 blocks (was 12544). qkv loop = R18 1-barrier (74.5 us).

#define DM   1024
#define NH   16
#define HD   64
#define SEQL 2048
#define BATCH 4
#define QKV_ELEMS 8388608           // 4*16*2048*64 per tensor

using short8 = __attribute__((ext_vector_type(8))) short;
using f32x4  = __attribute__((ext_vector_type(4))) float;
typedef unsigned short u16;

// s_waitcnt with only vmcnt active: expcnt=7, lgkmcnt=15 (no-wait)
#define WAIT_VM(n) __builtin_amdgcn_s_waitcnt(0x0F70 | (n))
// s_waitcnt lgkmcnt(0) only: vmcnt=63, expcnt=7
#define WAIT_LGKM0() __builtin_amdgcn_s_waitcnt(0xC07F)
#define BARRIER()  __builtin_amdgcn_s_barrier()

// hardware packed f32->bf16 (RNE), 1 instruction per pair (T12 recipe; no builtin)
__device__ __forceinline__ unsigned cvtpk(float lo, float hi) {
    unsigned r;
    asm("v_cvt_pk_bf16_f32 %0, %1, %2" : "=v"(r) : "v"(lo), "v"(hi));
    return r;
}
__device__ __forceinline__ u16 f2bf1(float x) {
    unsigned r;
    asm("v_cvt_pk_bf16_f32 %0, %1, %1" : "=v"(r) : "v"(x));
    return (u16)r;
}
__device__ __forceinline__ float fexp2(float x) {
#if __has_builtin(__builtin_amdgcn_exp2f)
    return __builtin_amdgcn_exp2f(x);
#else
    return __expf(x * 0.6931471805599453f);
#endif
}

// async global->LDS, 16B per lane; LDS dest = wave-uniform base + lane*16
__device__ __forceinline__ void load16(const void* g, void* l) {
    __builtin_amdgcn_global_load_lds(
        (__attribute__((address_space(1))) unsigned int*)(unsigned long long)g,
        (__attribute__((address_space(3))) unsigned int*)(unsigned int)(unsigned long long)l,
        16, 0, 0);
}

// ---------------- prep: fp32->bf16 (x, qkv_w, o_w) + RoPE float2 table --------
// R19: grid-stride, 2048 conversion blocks (6 float4/thread) + 256 table blocks.
__global__ __launch_bounds__(256) void prep(const float* __restrict__ x, u16* __restrict__ xb,
                                            const float* __restrict__ qw, u16* __restrict__ wb,
                                            const float* __restrict__ ow, u16* __restrict__ owb,
                                            float2* __restrict__ cst) {
    int bx = blockIdx.x;
    if (bx < 2048) {
        int base = bx * 256 + threadIdx.x;       // 0..524287
#pragma unroll
        for (int k = 0; k < 6; ++k) {
            int i = base + k * 524288;           // < 3145728 total float4s
            const float* in; u16* out; int idx;
            if (i < 2097152)      { in = x;  out = xb;  idx = i; }
            else if (i < 2883584) { in = qw; out = wb;  idx = i - 2097152; }
            else                  { in = ow; out = owb; idx = i - 2883584; }
            float4 v = ((const float4*)in)[idx];
            uint2 o;
            o.x = cvtpk(v.x, v.y);
            o.y = cvtpk(v.z, v.w);
            ((uint2*)out)[idx] = o;
        }
    } else {
        int t = (bx - 2048) * 256 + threadIdx.x;   // 65536 = 2048 pos x 32 d2
        int j = t & 31, pos = t >> 5;
        float freq = exp2f((float)j * (-2.0f / 64.0f) * 13.287712379549449f);
        float ang = (float)pos * freq;
        float2 cs; cs.x = cosf(ang); cs.y = sinf(ang);
        cst[t] = cs;
    }
}

// ---------------- 128x128-tile bf16 GEMM core, BK=32, triple-buffered ----------
__device__ __forceinline__ void gemm128_core(const u16* __restrict__ A,
                                             const u16* __restrict__ B,
                                             int K, int m0, int n0,
                                             u16* As, u16* Bs, f32x4 acc[4][4]) {
    int tid = threadIdx.x, w = tid >> 6, l = tid & 63;
    int l15 = l & 15, l4 = l >> 4;
    int wm = w >> 1, wn = w & 1;
    int r0 = 32 * w + (l >> 2);
    int gblk = ((l & 3) ^ ((l >> 4) & 3)) * 8;
    const u16* gA0 = A + (size_t)(m0 + r0) * K + gblk;
    const u16* gA1 = gA0 + (size_t)16 * K;
    const u16* gB0 = B + (size_t)(n0 + r0) * K + gblk;
    const u16* gB1 = gB0 + (size_t)16 * K;
    char* ldsA = (char*)As + 2048 * w;
    char* ldsB = (char*)Bs + 2048 * w;
    int fo = ((l4 ^ (l15 >> 2)) & 3) * 16;
    f32x4 z = {0.f, 0.f, 0.f, 0.f};
#pragma unroll
    for (int i = 0; i < 4; ++i)
#pragma unroll
        for (int j = 0; j < 4; ++j) acc[i][j] = z;
    int nk = K >> 5;
#pragma unroll
    for (int t = 0; t < 2; ++t) {
        int ko = t << 5, nb = t * 8192;
        load16(gA0 + ko, ldsA + nb); load16(gA1 + ko, ldsA + nb + 1024);
        load16(gB0 + ko, ldsB + nb); load16(gB1 + ko, ldsB + nb + 1024);
    }
    int buf = 0;
    for (int kt = 0; kt < nk; ++kt) {
        if (kt < nk - 1) WAIT_VM(4); else WAIT_VM(0);
        BARRIER();
        if (kt + 2 < nk) {
            int ko = (kt + 2) << 5;
            int nb = 8192 * ((buf + 2) % 3);
            load16(gA0 + ko, ldsA + nb); load16(gA1 + ko, ldsA + nb + 1024);
            load16(gB0 + ko, ldsB + nb); load16(gB1 + ko, ldsB + nb + 1024);
        }
        const char* bA = (const char*)As + 8192 * buf;
        const char* bB = (const char*)Bs + 8192 * buf;
        short8 a[4], b[4];
#pragma unroll
        for (int i = 0; i < 4; ++i)
            a[i] = *(const short8*)(bA + (64 * wm + 16 * i + l15) * 64 + fo);
#pragma unroll
        for (int j = 0; j < 4; ++j)
            b[j] = *(const short8*)(bB + (64 * wn + 16 * j + l15) * 64 + fo);
#pragma unroll
        for (int i = 0; i < 4; ++i)
#pragma unroll
            for (int j = 0; j < 4; ++j)
                acc[i][j] = __builtin_amdgcn_mfma_f32_16x16x32_bf16(a[i], b[j], acc[i][j], 0, 0, 0);
        buf = (buf + 1) % 3;
    }
}

// -------- QKV GEMM (256^2 tile, R18 1-barrier loop): Q,K + RoPE; V -> vt ------
__global__ __launch_bounds__(512, 2) void gemm_qkv(const u16* __restrict__ xb,
                                                   const u16* __restrict__ wb,
                                                   u16* __restrict__ qkv,
                                                   u16* __restrict__ vt,
                                                   const int* __restrict__ pos_ids,
                                                   const float2* __restrict__ cst) {
    __shared__ __align__(16) u16 As[3 * 256 * 32];   // 48 KB
    __shared__ __align__(16) u16 Bs[3 * 256 * 32];   // 48 KB
    int tid = threadIdx.x, w = tid >> 6, l = tid & 63;
    int l15 = l & 15, l4 = l >> 4;
    int wr = w >> 2, wc = w & 3;

    // XCD-chunked bijective swizzle: 384 blocks, 8 XCDs -> 48 per chunk.
    int bid = blockIdx.y * 12 + blockIdx.x;
    int swz = (bid & 7) * 48 + (bid >> 3);
    int nI = swz % 12, mI = swz / 12;
    int m0 = mI * 256, n0 = nI * 256;

    int schunk = ((l & 3) ^ ((l >> 3) & 3)) * 8;
    const u16* gA = xb + (size_t)(m0 + 32 * w + (l >> 2)) * DM + schunk;
    const u16* gB = wb + (size_t)(n0 + 32 * w + (l >> 2)) * DM + schunk;
    char* ldsA = (char*)As + 2048 * w;
    char* ldsB = (char*)Bs + 2048 * w;

    int roff = (l4 ^ ((l15 >> 1) & 3)) * 16;
    int aoff = (128 * wr + l15) * 64 + roff;
    int boff = (64 * wc + l15) * 64 + roff;

    f32x4 acc[8][4];
    f32x4 z = {0.f, 0.f, 0.f, 0.f};
#pragma unroll
    for (int i = 0; i < 8; ++i)
#pragma unroll
        for (int j = 0; j < 4; ++j) acc[i][j] = z;

    // prologue: stage tiles 0,1 -> bufs 0,1
#pragma unroll
    for (int t = 0; t < 2; ++t) {
        load16(gA + t * 32,           ldsA + t * 16384);
        load16(gA + t * 32 + 16 * DM, ldsA + t * 16384 + 1024);
        load16(gB + t * 32,           ldsB + t * 16384);
        load16(gB + t * 32 + 16 * DM, ldsB + t * 16384 + 1024);
    }
    WAIT_VM(4);        // tile0 landed; tile1 (4 loads) still in flight
    BARRIER();

    int buf = 0;
    for (int kt = 0; kt < 32; ++kt) {
        const char* bA = (const char*)As + 16384 * buf;
        const char* bB = (const char*)Bs + 16384 * buf;
        int nb = buf + 2; if (nb >= 3) nb -= 3;
        // ds-read all 12 fragments of this tile
        short8 a[8], b[4];
#pragma unroll
        for (int i = 0; i < 8; ++i) a[i] = *(const short8*)(bA + aoff + 1024 * i);
#pragma unroll
        for (int j = 0; j < 4; ++j) b[j] = *(const short8*)(bB + boff + 1024 * j);
        // stage tile kt+2 (A + B, 4 loads) -- targets buffer nb != buf
        if (kt + 2 < 32) {
            load16(gA + (kt + 2) * 32,           ldsA + nb * 16384);
            load16(gA + (kt + 2) * 32 + 16 * DM, ldsA + nb * 16384 + 1024);
            load16(gB + (kt + 2) * 32,           ldsB + nb * 16384);
            load16(gB + (kt + 2) * 32 + 16 * DM, ldsB + nb * 16384 + 1024);
        }
        WAIT_LGKM0();            // frags in regs (reads of buf complete)
        __builtin_amdgcn_s_setprio(1);
#pragma unroll
        for (int i = 0; i < 8; ++i)
#pragma unroll
            for (int j = 0; j < 4; ++j)
                acc[i][j] = __builtin_amdgcn_mfma_f32_16x16x32_bf16(a[i], b[j], acc[i][j], 0, 0, 0);
        __builtin_amdgcn_s_setprio(0);
        // drain tile kt+1's loads (issued last tile); kt+2's 4 may stay in flight
        if (kt + 2 < 32) WAIT_VM(4); else WAIT_VM(0);
        BARRIER();               // separates reads of buf from next tile's overwrite
        buf = (kt + 1) % 3;
    }

    // ---- epilogue ----  C elem: m = m0+128wr+16i+4*l4+r,  n = n0+64wc+16j+l15
    if (nI >= 8) {
#pragma unroll
        for (int j = 0; j < 4; ++j) {
            int nv = (n0 - 2048) + 64 * wc + 16 * j + l15;
            int h = nv >> 6, d = nv & 63;
#pragma unroll
            for (int i = 0; i < 8; ++i) {
                int sb = m0 + 128 * wr + 16 * i + 4 * l4;
                int bb = sb >> 11, s = sb & 2047;
                uint2 pk;
                pk.x = cvtpk(acc[i][j][0], acc[i][j][1]);
                pk.y = cvtpk(acc[i][j][2], acc[i][j][3]);
                *(uint2*)&vt[((size_t)(bb * 16 + h) * HD + d) * SEQL + s] = pk;
            }
        }
    } else {
        float sc = (nI < 4) ? 0.18033688011112042f : 1.0f;
        u16* base = qkv + (size_t)(nI >> 2) * QKV_ELEMS;
        int h = ((n0 & 1023) >> 6) + wc;
        int d2b = l15 >> 1;
#pragma unroll
        for (int i = 0; i < 8; ++i) {
#pragma unroll
            for (int r = 0; r < 4; ++r) {
                int m = m0 + 128 * wr + 16 * i + 4 * l4 + r;
                int bb = m >> 11, s = m & 2047;
                int pos = pos_ids[s];
                const float2* ct = cst + pos * 32;
                float2 tt[4];
                tt[0] = ct[d2b];      tt[1] = ct[8 + d2b];
                tt[2] = ct[16 + d2b]; tt[3] = ct[24 + d2b];
                u16* orow = base + ((size_t)(bb * 16 + h) * SEQL + s) * HD;
#pragma unroll
                for (int j = 0; j < 4; ++j) {
                    int d = 16 * j + l15;
                    float c  = tt[j].x;
                    float sn = tt[j].y;
                    float v  = acc[i][j][r];
                    float vp = __shfl_xor(v, 1);
                    float o  = (d & 1) ? (vp * sn + v * c) : (v * c - vp * sn);
                    orow[d] = f2bf1(o * sc);
                }
            }
        }
    }
}

// ---------------- out-proj GEMM (R12 core + R19 XCD swizzle): fp32 out --------
__global__ __launch_bounds__(256) void gemm_out(const u16* __restrict__ ctx,
                                                const u16* __restrict__ owb,
                                                float* __restrict__ out) {
    __shared__ __align__(16) u16 As[3 * 128 * 32], Bs[3 * 128 * 32];
    f32x4 acc[4][4];
    // XCD-chunked bijective swizzle: 512 blocks, 8 XCDs -> 64 per chunk.
    // XCD c covers mI in [8c, 8c+8) x all 8 nI: A-slab 2MB + B 2MB ~= L2.
    int bid = blockIdx.x + blockIdx.y * 8;
    int s = (bid & 7) * 64 + (bid >> 3);
    int m0 = (s >> 3) * 128, n0 = (s & 7) * 128;
    gemm128_core(ctx, owb, DM, m0, n0, As, Bs, acc);
    int l = threadIdx.x & 63, w = threadIdx.x >> 6;
    int l15 = l & 15, l4 = l >> 4;
    int wm = w >> 1, wn = w & 1;
#pragma unroll
    for (int i = 0; i < 4; ++i) {
        int mb = m0 + 64 * wm + 16 * i + 4 * l4;
#pragma unroll
        for (int j = 0; j < 4; ++j) {
            int n = n0 + 64 * wn + 16 * j + l15;
#pragma unroll
            for (int r = 0; r < 4; ++r)
                out[(size_t)(mb + r) * DM + n] = acc[i][j][r];
        }
    }
}

// ---------------- flash attention v7: q-tile 256, 8 waves x 2 groups ----------
// Wave w: q-rows q0+128g+16w..+15 for g in {0,1}. K/V frags loaded once per
// iter, shared by both groups. Fixed-max softmax (Q prescaled).
// Dual P-buffers; ordering S0/write0 -> S1/write1 -> vf -> PV0 -> PV1;
// setprio around MFMA clusters; P-pack via v_cvt_pk_bf16_f32.
__device__ __forceinline__ void flash_pass(int qt, const u16* __restrict__ Qb,
                                           const u16* __restrict__ Kb,
                                           const u16* __restrict__ Vb,
                                           u16* __restrict__ ctx, int bh,
                                           u16* KsB, u16* VsB, u16* PsB) {
    int tid = threadIdx.x, w = tid >> 6, l = tid & 63;
    int l15 = l & 15, l4 = l >> 4;
    int q0 = qt * 256;
    int swz = l15 & 7;
    int b0 = (l4 ^ swz) * 16;

    short8 aq[2][2];
#pragma unroll
    for (int g = 0; g < 2; ++g) {
        const u16* qr = Qb + (size_t)(q0 + 128 * g + 16 * w + l15) * HD;
        aq[g][0] = *(const short8*)&qr[l4 * 8];
        aq[g][1] = *(const short8*)&qr[32 + l4 * 8];
    }
    int srow = l >> 3;
    int sblk = ((l & 7) ^ srow) * 8;
    const u16* gK = Kb + (size_t)(8 * w + srow) * HD + sblk;
    const u16* gV = Vb + (size_t)(8 * w + srow) * SEQL + sblk;
    char* ldsK = (char*)KsB + 1024 * w;
    char* ldsV = (char*)VsB + 1024 * w;
    char* prow0 = (char*)PsB + 2048 * w + l15 * 128;
    char* prow1 = prow0 + 16384;

    f32x4 z = {0.f, 0.f, 0.f, 0.f};
    f32x4 O[2][4] = {{z, z, z, z}, {z, z, z, z}};
    float lsum[2] = {0.f, 0.f};
    int nk = 4 * qt + 4;
    int d0 = 4 * qt + (w >> 2);        // g0 diagonal iter (g1: +2)
    int rowlim = 16 * (w & 3) + l15;

    BARRIER();   // prior pass's LDS reads consumed
#pragma unroll
    for (int t = 0; t < 2; ++t) {
        load16(gK + (size_t)(t * 64) * HD, ldsK + t * 8192);
        load16(gV + t * 64,                ldsV + t * 8192);
    }
    int buf = 0;
    for (int it = 0; it < nk; ++it) {
        if (it < nk - 1) WAIT_VM(2); else WAIT_VM(0);
        BARRIER();
        if (it + 2 < nk) {
            int k0n = (it + 2) * 64;
            int nb = 8192 * ((buf + 2) % 3);
            load16(gK + (size_t)k0n * HD, ldsK + nb);
            load16(gV + k0n,              ldsV + nb);
        }
        if (it <= d0 + 2) {            // else: both groups fully masked
            const char* bK = (const char*)KsB + 8192 * buf;
            const char* bV = (const char*)VsB + 8192 * buf;
            bool g0act = (it <= d0);
            short8 kf[4][2];
#pragma unroll
            for (int c = 0; c < 4; ++c) {
                const char* kr = bK + (16 * c + l15) * 128;
                kf[c][0] = *(const short8*)(kr + b0);
                kf[c][1] = *(const short8*)(kr + (b0 ^ 64));
            }
            // ---- group 0: S, softmax, P-write ----
            if (g0act) {
                f32x4 S[4];
                __builtin_amdgcn_s_setprio(1);
#pragma unroll
                for (int c = 0; c < 4; ++c) {
                    S[c] = __builtin_amdgcn_mfma_f32_16x16x32_bf16(kf[c][0], aq[0][0], z, 0, 0, 0);
                    S[c] = __builtin_amdgcn_mfma_f32_16x16x32_bf16(kf[c][1], aq[0][1], S[c], 0, 0, 0);
                }
                __builtin_amdgcn_s_setprio(0);
                if (it == d0) {
#pragma unroll
                    for (int c = 0; c < 4; ++c)
#pragma unroll
                        for (int r = 0; r < 4; ++r)
                            if (16 * c + 4 * l4 + r > rowlim) S[c][r] = -3e38f;
                }
                float ls = 0.f;
#pragma unroll
                for (int c = 0; c < 4; ++c) {
                    float cs = 0.f;
#pragma unroll
                    for (int r = 0; r < 4; ++r) {
                        float p = fexp2(S[c][r]);
                        S[c][r] = p;
                        cs += p;
                    }
                    ls += cs;
                    uint2 pk;
                    pk.x = cvtpk(S[c][0], S[c][1]);
                    pk.y = cvtpk(S[c][2], S[c][3]);
                    *(uint2*)(prow0 + ((((2 * c + (l4 >> 1)) ^ swz) << 4) | ((l4 & 1) << 3))) = pk;
                }
                lsum[0] += ls;
            }
            // ---- group 1: S, softmax, P-write (always active under guard) ----
            {
                f32x4 S[4];
                __builtin_amdgcn_s_setprio(1);
#pragma unroll
                for (int c = 0; c < 4; ++c) {
                    S[c] = __builtin_amdgcn_mfma_f32_16x16x32_bf16(kf[c][0], aq[1][0], z, 0, 0, 0);
                    S[c] = __builtin_amdgcn_mfma_f32_16x16x32_bf16(kf[c][1], aq[1][1], S[c], 0, 0, 0);
                }
                __builtin_amdgcn_s_setprio(0);
                if (it == d0 + 2) {
#pragma unroll
                    for (int c = 0; c < 4; ++c)
#pragma unroll
                        for (int r = 0; r < 4; ++r)
                            if (16 * c + 4 * l4 + r > rowlim) S[c][r] = -3e38f;
                }
                float ls = 0.f;
#pragma unroll
                for (int c = 0; c < 4; ++c) {
                    float cs = 0.f;
#pragma unroll
                    for (int r = 0; r < 4; ++r) {
                        float p = fexp2(S[c][r]);
                        S[c][r] = p;
                        cs += p;
                    }
                    ls += cs;
                    uint2 pk;
                    pk.x = cvtpk(S[c][0], S[c][1]);
                    pk.y = cvtpk(S[c][2], S[c][3]);
                    *(uint2*)(prow1 + ((((2 * c + (l4 >> 1)) ^ swz) << 4) | ((l4 & 1) << 3))) = pk;
                }
                lsum[1] += ls;
            }
            // ---- V frags (between writes and reads: more latency cover) ----
            short8 vf[4][2];
#pragma unroll
            for (int c = 0; c < 4; ++c) {
                const char* vr = bV + (16 * c + l15) * 128;
                vf[c][0] = *(const short8*)(vr + b0);
                vf[c][1] = *(const short8*)(vr + (b0 ^ 64));
            }
            // ---- PV group 0 ----
            if (g0act) {
                short8 ap0 = *(const short8*)(prow0 + b0);
                short8 ap1 = *(const short8*)(prow0 + (b0 ^ 64));
                __builtin_amdgcn_s_setprio(1);
#pragma unroll
                for (int nt = 0; nt < 4; ++nt) {
                    O[0][nt] = __builtin_amdgcn_mfma_f32_16x16x32_bf16(ap0, vf[nt][0], O[0][nt], 0, 0, 0);
                    O[0][nt] = __builtin_amdgcn_mfma_f32_16x16x32_bf16(ap1, vf[nt][1], O[0][nt], 0, 0, 0);
                }
                __builtin_amdgcn_s_setprio(0);
            }
            // ---- PV group 1 ----
            {
                short8 bp0 = *(const short8*)(prow1 + b0);
                short8 bp1 = *(const short8*)(prow1 + (b0 ^ 64));
                __builtin_amdgcn_s_setprio(1);
#pragma unroll
                for (int nt = 0; nt < 4; ++nt) {
                    O[1][nt] = __builtin_amdgcn_mfma_f32_16x16x32_bf16(bp0, vf[nt][0], O[1][nt], 0, 0, 0);
                    O[1][nt] = __builtin_amdgcn_mfma_f32_16x16x32_bf16(bp1, vf[nt][1], O[1][nt], 0, 0, 0);
                }
                __builtin_amdgcn_s_setprio(0);
            }
        }
        buf = (buf + 1) % 3;
    }
    // epilogue: ctx[b][s][h*64+d] bf16
    int b = bh >> 4, h = bh & 15;
#pragma unroll
    for (int g = 0; g < 2; ++g) {
        float ls = lsum[g];
        ls += __shfl_xor(ls, 16);
        ls += __shfl_xor(ls, 32);
        float linv[4];
#pragma unroll
        for (int r = 0; r < 4; ++r) linv[r] = 1.0f / __shfl(ls, 20 * l4 + r);
#pragma unroll
        for (int nt = 0; nt < 4; ++nt) {
            int d = 16 * nt + l15;
#pragma unroll
            for (int r = 0; r < 4; ++r) {
                int s = q0 + 128 * g + 16 * w + 4 * l4 + r;
                ctx[((size_t)(b * SEQL + s)) * DM + h * 64 + d] = f2bf1(O[g][nt][r] * linv[r]);
            }
        }
    }
}

// R19: XCD-clustered bijective remap -- XCD c (= id&7 under round-robin
// dispatch) owns bh {c, c+8, ..., c+56}: 8 x 512KB K/V = 4MB = one L2.
// Within a block: q-tiles (7-pair) then pair -> uniform 36 iters.
__global__ __launch_bounds__(512, 2) void flash_attn(const u16* __restrict__ Q,
                                                     const u16* __restrict__ K,
                                                     const u16* __restrict__ Vt,
                                                     u16* __restrict__ ctx) {
    __shared__ __align__(16) u16 Ks[3][64 * 64];      // 24 KB
    __shared__ __align__(16) u16 Vs[3][64 * 64];      // 24 KB
    __shared__ __align__(16) u16 Ps[2][8][16 * 64];   // 32 KB (dual P buffers)
    int id = blockIdx.x + blockIdx.y * 4;     // dispatch-linear (x fastest)
    int xcd = id & 7, k = id >> 3;            // k: 0..31
    int bh = (k >> 2) * 8 + xcd;              // 8 bh per XCD
    int pair = k & 3;
    const u16* Qb = Q + (size_t)bh * SEQL * HD;
    const u16* Kb = K + (size_t)bh * SEQL * HD;
    const u16* Vb = Vt + (size_t)bh * HD * SEQL;
    flash_pass(7 - pair, Qb, Kb, Vb, ctx, bh, &Ks[0][0], &Vs[0][0], &Ps[0][0][0]);
    flash_pass(pair,     Qb, Kb, Vb, ctx, bh, &Ks[0][0], &Vs[0][0], &Ps[0][0][0]);
}

extern "C" void kernel_launch(void* const* d_in, const int* in_sizes, int n_in,
                              void* d_out, int out_size, void* d_ws, size_t ws_size,
                              hipStream_t stream) {
    const float* x     = (const float*)d_in[0];
    const int*   pos   = (const int*)d_in[1];
    const float* qkv_w = (const float*)d_in[2];
    const float* o_w   = (const float*)d_in[3];
    float* out = (float*)d_out;

    char* ws = (char*)d_ws;
    u16*    xb  = (u16*)(ws);              // 16 MB (reused as ctx)
    u16*    wb  = (u16*)(ws + 16777216);   // 6 MB
    u16*    owb = (u16*)(ws + 23068672);   // 2 MB
    float2* cst = (float2*)(ws + 25165824);// 512 KB (cos,sin interleaved)
    u16*    qkv = (u16*)(ws + 25690112);   // 32 MB (Q,K)
    u16*    vt  = (u16*)(ws + 76021760);   // 16 MB
    u16*    ctx = xb;                      // alias: xb dead after gemm_qkv

    prep<<<2304, 256, 0, stream>>>(x, xb, qkv_w, wb, o_w, owb, cst);
    gemm_qkv<<<dim3(12, 32), 512, 0, stream>>>(xb, wb, qkv, vt, pos, cst);
    flash_attn<<<dim3(4, 64), 512, 0, stream>>>(qkv, qkv + QKV_ELEMS, vt, ctx);
    gemm_out<<<dim3(8, 64), 256, 0, stream>>>(ctx, owb, out);
}